// Round 4
// baseline (628.096 us; speedup 1.0000x reference)
//
#include <hip/hip_runtime.h>
#include <hip/hip_bf16.h>
#include <stdint.h>
#include <math.h>

#define SEQ 2048
#define NTOK 8192        // B*S
#define EMB 1024
#define NH 16
#define HD 64
#define FFD 4096
#define QSCALE 0.1803368801111137f   // 0.125 * log2(e), folded into Wq/bq

using us = unsigned short;
using b8 = __attribute__((ext_vector_type(8))) __bf16;
using f4 = __attribute__((ext_vector_type(4))) float;

__device__ __forceinline__ us f2b(float f) {
  union { float f; uint32_t u; } v; v.f = f;
  uint32_t u = v.u;
  return (us)((u + 0x7fffu + ((u >> 16) & 1u)) >> 16);  // RNE
}

// pack two fp32 -> bf16x2 (round-half-up; P >= 0, bias negligible)
__device__ __forceinline__ uint32_t pkbf(float a, float b) {
  union { float f; uint32_t u; } x, y; x.f = a; y.f = b;
  return ((x.u + 0x8000u) >> 16) | ((y.u + 0x8000u) & 0xFFFF0000u);
}

__device__ __forceinline__ void async16(void* lds, const void* g) {
  __builtin_amdgcn_global_load_lds(
      (__attribute__((address_space(1))) void*)(uintptr_t)g,
      (__attribute__((address_space(3))) void*)(uintptr_t)lds, 16, 0, 0);
}

#define FENCED_BARRIER() do { asm volatile("" ::: "memory"); \
  __builtin_amdgcn_s_barrier(); asm volatile("" ::: "memory"); } while (0)

// tanh-form GELU: 0.5x(1+tanh(k0(x+k1 x^3))) = x*sigmoid(2 k0 (x+k1 x^3))
// |err vs exact erf-gelu| < ~1e-3, below ff1's bf16 quantization.
__device__ __forceinline__ float gelu_f(float x) {
  const float z = -2.30211416f * x * (1.f + 0.044715f * x * x);
  return x / (1.f + __builtin_amdgcn_exp2f(z));
}

// ---------------- transpose + cast (+scale): in [R][C] f32 -> out [C][R] bf16 ----------------
__global__ __launch_bounds__(256)
void transpose_cast(const float* __restrict__ in, us* __restrict__ out, int R, int C,
                    float scale) {
  __shared__ float tile[32][33];
  const int bc = blockIdx.x * 32, br = blockIdx.y * 32;
  const int tx = threadIdx.x & 31, ty = threadIdx.x >> 5;
#pragma unroll
  for (int i = 0; i < 32; i += 8)
    tile[ty + i][tx] = in[(size_t)(br + ty + i) * C + bc + tx];
  __syncthreads();
#pragma unroll
  for (int i = 0; i < 32; i += 8)
    out[(size_t)(bc + ty + i) * R + br + tx] = f2b(tile[tx][ty + i] * scale);
}

// ---------------- pack bq|bk|bv into one [3072]; bq pre-scaled by QSCALE ----------------
__global__ void pack_bias(const float* __restrict__ bq, const float* __restrict__ bk,
                          const float* __restrict__ bv, float* __restrict__ o) {
  int i = blockIdx.x * 256 + threadIdx.x;
  o[i] = (i < 1024) ? bq[i] * QSCALE : (i < 2048 ? bk[i - 1024] : bv[i - 2048]);
}

// ---------------- LayerNorm: fp32 in -> bf16 out, one block per token ----------------
__global__ __launch_bounds__(256)
void ln_kernel(const float* __restrict__ x, const float* __restrict__ g,
               const float* __restrict__ be, us* __restrict__ out) {
  __shared__ float red[8];
  const int row = blockIdx.x, t = threadIdx.x;
  const float4 v = ((const float4*)(x + (size_t)row * EMB))[t];
  float s = v.x + v.y + v.z + v.w;
  float s2 = v.x * v.x + v.y * v.y + v.z * v.z + v.w * v.w;
#pragma unroll
  for (int o = 32; o; o >>= 1) { s += __shfl_down(s, o, 64); s2 += __shfl_down(s2, o, 64); }
  if ((t & 63) == 0) { red[(t >> 6) * 2] = s; red[(t >> 6) * 2 + 1] = s2; }
  __syncthreads();
  const float ts = red[0] + red[2] + red[4] + red[6];
  const float ts2 = red[1] + red[3] + red[5] + red[7];
  const float mu = ts * (1.f / 1024.f);
  const float rs = rsqrtf(ts2 * (1.f / 1024.f) - mu * mu + 1e-5f);
  const float4 gv = ((const float4*)g)[t];
  const float4 bv = ((const float4*)be)[t];
  ushort4 o4;
  o4.x = f2b((v.x - mu) * rs * gv.x + bv.x);
  o4.y = f2b((v.y - mu) * rs * gv.y + bv.y);
  o4.z = f2b((v.z - mu) * rs * gv.z + bv.z);
  o4.w = f2b((v.w - mu) * rs * gv.w + bv.w);
  ((ushort4*)(out + (size_t)row * EMB))[t] = o4;
}

// ================= 8-phase GEMM, BM=256 x BN=256, BK=64, 8 waves (2M x 4N) =================
// (unchanged from round 3 -- see comments there; vmcnt(6) counted pipeline, T2 XOR swizzle)
__global__ __launch_bounds__(512, 2)
void gemm256(const us* __restrict__ A, const us* __restrict__ Bt,
             const float* __restrict__ bias, us* __restrict__ outB,
             int N, int K, int gelu, int gy) {
  __shared__ us As[2][256 * 64];   // 64 KB
  __shared__ us Bs[2][256 * 64];   // 64 KB

  int bid = blockIdx.x;
  const int cpx = (int)gridDim.x >> 3;         // grid % 8 == 0 always here
  bid = (bid & 7) * cpx + (bid >> 3);          // bijective XCD swizzle
  const int bx = bid / gy, by = bid - bx * gy;
  const int row0 = bx * 256, col0 = by * 256;

  const int tid = threadIdx.x, w = tid >> 6, lane = tid & 63;
  const int wm = w >> 2, wn = w & 3;
  const int quad = lane >> 4, l15 = lane & 15;
  const int xr = l15 & 7;

  const int u0 = w * 2, u1 = u0 + 1;
  const int ar0 = ((u0 & 7) << 3) + ((u0 >> 3) << 7);   // A: {0..56} + {0,128}
  const int ar1 = ((u1 & 7) << 3) + ((u1 >> 3) << 7);
  const int br0 = ((u0 & 3) << 3) + ((u0 >> 2) << 6);   // B: {0..24} + {0,64,128,192}
  const int br1 = ((u1 & 3) << 3) + ((u1 >> 2) << 6);
  const int lrow = lane >> 3;
  const int loct = ((lane & 7) ^ lrow) << 3;            // inverse-swizzled source octet
  const us* Ag0 = A + (size_t)(row0 + ar0 + lrow) * K + loct;
  const us* Ag1 = A + (size_t)(row0 + ar1 + lrow) * K + loct;
  const us* Bg0 = Bt + (size_t)(col0 + br0 + lrow) * K + loct;
  const us* Bg1 = Bt + (size_t)(col0 + br1 + lrow) * K + loct;
  const int NT = K >> 6;

  const f4 zf = {0.f, 0.f, 0.f, 0.f};
  f4 acc[8][4];
#pragma unroll
  for (int i = 0; i < 8; i++)
#pragma unroll
    for (int j = 0; j < 4; j++) acc[i][j] = zf;

  auto stgA = [&](int buf, int t, int mh) {
    const size_t go = (size_t)(mh << 6) * K + ((size_t)t << 6);
    async16(&As[buf][(ar0 + (mh << 6)) << 6], Ag0 + go);
    async16(&As[buf][(ar1 + (mh << 6)) << 6], Ag1 + go);
  };
  auto stgB = [&](int buf, int t, int nh) {
    const size_t go = (size_t)(nh << 5) * K + ((size_t)t << 6);
    async16(&Bs[buf][(br0 + (nh << 5)) << 6], Bg0 + go);
    async16(&Bs[buf][(br1 + (nh << 5)) << 6], Bg1 + go);
  };

  stgA(0, 0, 0); stgB(0, 0, 0); stgB(0, 0, 1); stgA(0, 0, 1);
  stgA(1, 1, 0); stgB(1, 1, 0); stgB(1, 1, 1);
  asm volatile("s_waitcnt vmcnt(6)" ::: "memory");
  FENCED_BARRIER();

  for (int t = 0; t < NT; t++) {
    const int cur = t & 1, nxt = cur ^ 1;
    const us* __restrict__ as = As[cur];
    const us* __restrict__ bs = Bs[cur];
    b8 af[2][4], bf0[2][2], bf1[2][2];

    // ---- phase 1 (mh0, nh0): 12 ds_reads, stage U4(t+1)
#pragma unroll
    for (int s = 0; s < 2; s++) {
      const int po = (((s << 2) + quad) ^ xr) << 3;
#pragma unroll
      for (int mi = 0; mi < 4; mi++)
        af[s][mi] = *(const b8*)&as[(wm * 128 + mi * 16 + l15) * 64 + po];
#pragma unroll
      for (int nf = 0; nf < 2; nf++)
        bf0[s][nf] = *(const b8*)&bs[(wn * 64 + nf * 16 + l15) * 64 + po];
    }
    if (t + 1 < NT) stgA(nxt, t + 1, 1);
    FENCED_BARRIER();
    asm volatile("s_waitcnt lgkmcnt(0)" ::: "memory");
    __builtin_amdgcn_s_setprio(1);
#pragma unroll
    for (int s = 0; s < 2; s++)
#pragma unroll
      for (int mi = 0; mi < 4; mi++)
#pragma unroll
        for (int nf = 0; nf < 2; nf++)
          acc[mi][nf] = __builtin_amdgcn_mfma_f32_16x16x32_bf16(af[s][mi], bf0[s][nf], acc[mi][nf], 0, 0, 0);
    __builtin_amdgcn_s_setprio(0);
    FENCED_BARRIER();

    // ---- phase 2 (mh0, nh1): 4 ds_reads, stage U1(t+2)
#pragma unroll
    for (int s = 0; s < 2; s++) {
      const int po = (((s << 2) + quad) ^ xr) << 3;
#pragma unroll
      for (int nf = 0; nf < 2; nf++)
        bf1[s][nf] = *(const b8*)&bs[(wn * 64 + 32 + nf * 16 + l15) * 64 + po];
    }
    if (t + 2 < NT) stgA(cur, t + 2, 0);
    FENCED_BARRIER();
    asm volatile("s_waitcnt lgkmcnt(0)" ::: "memory");
    __builtin_amdgcn_s_setprio(1);
#pragma unroll
    for (int s = 0; s < 2; s++)
#pragma unroll
      for (int mi = 0; mi < 4; mi++)
#pragma unroll
        for (int nf = 0; nf < 2; nf++)
          acc[mi][2 + nf] = __builtin_amdgcn_mfma_f32_16x16x32_bf16(af[s][mi], bf1[s][nf], acc[mi][2 + nf], 0, 0, 0);
    __builtin_amdgcn_s_setprio(0);
    FENCED_BARRIER();

    // ---- phase 3 (mh1, nh0): 8 ds_reads, stage U2(t+2)
#pragma unroll
    for (int s = 0; s < 2; s++) {
      const int po = (((s << 2) + quad) ^ xr) << 3;
#pragma unroll
      for (int mi = 0; mi < 4; mi++)
        af[s][mi] = *(const b8*)&as[(wm * 128 + 64 + mi * 16 + l15) * 64 + po];
    }
    if (t + 2 < NT) stgB(cur, t + 2, 0);
    FENCED_BARRIER();
    asm volatile("s_waitcnt lgkmcnt(0)" ::: "memory");
    __builtin_amdgcn_s_setprio(1);
#pragma unroll
    for (int s = 0; s < 2; s++)
#pragma unroll
      for (int mi = 0; mi < 4; mi++)
#pragma unroll
        for (int nf = 0; nf < 2; nf++)
          acc[4 + mi][nf] = __builtin_amdgcn_mfma_f32_16x16x32_bf16(af[s][mi], bf0[s][nf], acc[4 + mi][nf], 0, 0, 0);
    __builtin_amdgcn_s_setprio(0);
    FENCED_BARRIER();

    // ---- phase 4 (mh1, nh1): 0 ds_reads, stage U3(t+2), once-per-tile vmcnt
    if (t + 2 < NT) {
      stgB(cur, t + 2, 1);
      asm volatile("s_waitcnt vmcnt(6)" ::: "memory");   // retires all of tile t+1
    } else {
      asm volatile("s_waitcnt vmcnt(0)" ::: "memory");
    }
    FENCED_BARRIER();
    __builtin_amdgcn_s_setprio(1);
#pragma unroll
    for (int s = 0; s < 2; s++)
#pragma unroll
      for (int mi = 0; mi < 4; mi++)
#pragma unroll
        for (int nf = 0; nf < 2; nf++)
          acc[4 + mi][2 + nf] = __builtin_amdgcn_mfma_f32_16x16x32_bf16(af[s][mi], bf1[s][nf], acc[4 + mi][2 + nf], 0, 0, 0);
    __builtin_amdgcn_s_setprio(0);
    FENCED_BARRIER();
  }

#pragma unroll
  for (int mi8 = 0; mi8 < 8; mi8++)
#pragma unroll
    for (int nf = 0; nf < 4; nf++) {
      const int gcol = col0 + wn * 64 + nf * 16 + l15;
      const float bc = bias[gcol];
#pragma unroll
      for (int r = 0; r < 4; r++) {
        const int grow = row0 + wm * 128 + mi8 * 16 + quad * 4 + r;
        float v = acc[mi8][nf][r] + bc;
        if (gelu) v = gelu_f(v);
        outB[(size_t)grow * N + gcol] = f2b(v);
      }
    }
}

// ================= 8-phase GEMM, BM=128 x BN=256 (f32 out + resid) ==================
// (unchanged from round 3)
__global__ __launch_bounds__(512, 2)
void gemm128(const us* __restrict__ A, const us* __restrict__ Bt,
             const float* __restrict__ bias, const float* __restrict__ resid,
             float* __restrict__ outF, int N, int K, int gy) {
  __shared__ us As[2][128 * 64];   // 32 KB
  __shared__ us Bs[2][256 * 64];   // 64 KB

  int bid = blockIdx.x;
  const int cpx = (int)gridDim.x >> 3;
  bid = (bid & 7) * cpx + (bid >> 3);
  const int bx = bid / gy, by = bid - bx * gy;
  const int row0 = bx * 128, col0 = by * 256;

  const int tid = threadIdx.x, w = tid >> 6, lane = tid & 63;
  const int wm = w >> 2, wn = w & 3;
  const int quad = lane >> 4, l15 = lane & 15;
  const int xr = l15 & 7;

  const int u0 = w * 2, u1 = u0 + 1;
  const int aR0 = u0 << 3, aR1 = u1 << 3;               // A rows 0..127
  const int bR0 = ((u0 & 3) << 3) + ((u0 >> 2) << 6);
  const int bR1 = ((u1 & 3) << 3) + ((u1 >> 2) << 6);
  const int lrow = lane >> 3;
  const int loct = ((lane & 7) ^ lrow) << 3;
  const us* Ag0 = A + (size_t)(row0 + aR0 + lrow) * K + loct;
  const us* Ag1 = A + (size_t)(row0 + aR1 + lrow) * K + loct;
  const us* Bg0 = Bt + (size_t)(col0 + bR0 + lrow) * K + loct;
  const us* Bg1 = Bt + (size_t)(col0 + bR1 + lrow) * K + loct;
  const int NT = K >> 6;

  const f4 zf = {0.f, 0.f, 0.f, 0.f};
  f4 acc[4][4];
#pragma unroll
  for (int i = 0; i < 4; i++)
#pragma unroll
    for (int j = 0; j < 4; j++) acc[i][j] = zf;

  auto stgA = [&](int buf, int t) {
    const size_t go = (size_t)t << 6;
    async16(&As[buf][aR0 << 6], Ag0 + go);
    async16(&As[buf][aR1 << 6], Ag1 + go);
  };
  auto stgB = [&](int buf, int t, int nh) {
    const size_t go = (size_t)(nh << 5) * K + ((size_t)t << 6);
    async16(&Bs[buf][(bR0 + (nh << 5)) << 6], Bg0 + go);
    async16(&Bs[buf][(bR1 + (nh << 5)) << 6], Bg1 + go);
  };

  stgA(0, 0); stgB(0, 0, 0); stgB(0, 0, 1);
  stgA(1, 1); stgB(1, 1, 0);
  asm volatile("s_waitcnt vmcnt(6)" ::: "memory");
  FENCED_BARRIER();

  for (int t = 0; t < NT; t++) {
    const int cur = t & 1, nxt = cur ^ 1;
    const us* __restrict__ as = As[cur];
    const us* __restrict__ bs = Bs[cur];
    b8 af[2][4], bf0[2][2], bf1[2][2];

    // ---- phase 1: 12 ds_reads, stage UB1(t+1), retire UB1(t)
#pragma unroll
    for (int s = 0; s < 2; s++) {
      const int po = (((s << 2) + quad) ^ xr) << 3;
#pragma unroll
      for (int mi = 0; mi < 4; mi++)
        af[s][mi] = *(const b8*)&as[(wm * 64 + mi * 16 + l15) * 64 + po];
#pragma unroll
      for (int nf = 0; nf < 2; nf++)
        bf0[s][nf] = *(const b8*)&bs[(wn * 64 + nf * 16 + l15) * 64 + po];
    }
    if (t + 1 < NT) {
      stgB(nxt, t + 1, 1);
      asm volatile("s_waitcnt vmcnt(6)" ::: "memory");
    } else {
      asm volatile("s_waitcnt vmcnt(0)" ::: "memory");
    }
    FENCED_BARRIER();
    asm volatile("s_waitcnt lgkmcnt(0)" ::: "memory");
    __builtin_amdgcn_s_setprio(1);
#pragma unroll
    for (int s = 0; s < 2; s++)
#pragma unroll
      for (int mi = 0; mi < 4; mi++)
#pragma unroll
        for (int nf = 0; nf < 2; nf++)
          acc[mi][nf] = __builtin_amdgcn_mfma_f32_16x16x32_bf16(af[s][mi], bf0[s][nf], acc[mi][nf], 0, 0, 0);
    __builtin_amdgcn_s_setprio(0);
    FENCED_BARRIER();

    // ---- phase 2: 4 ds_reads, stage UA(t+2)+UB0(t+2), retire UA,UB0(t+1)
#pragma unroll
    for (int s = 0; s < 2; s++) {
      const int po = (((s << 2) + quad) ^ xr) << 3;
#pragma unroll
      for (int nf = 0; nf < 2; nf++)
        bf1[s][nf] = *(const b8*)&bs[(wn * 64 + 32 + nf * 16 + l15) * 64 + po];
    }
    if (t + 2 < NT) {
      stgA(cur, t + 2); stgB(cur, t + 2, 0);
      asm volatile("s_waitcnt vmcnt(6)" ::: "memory");
    } else {
      asm volatile("s_waitcnt vmcnt(2)" ::: "memory");
    }
    FENCED_BARRIER();
    asm volatile("s_waitcnt lgkmcnt(0)" ::: "memory");
    __builtin_amdgcn_s_setprio(1);
#pragma unroll
    for (int s = 0; s < 2; s++)
#pragma unroll
      for (int mi = 0; mi < 4; mi++)
#pragma unroll
        for (int nf = 0; nf < 2; nf++)
          acc[mi][2 + nf] = __builtin_amdgcn_mfma_f32_16x16x32_bf16(af[s][mi], bf1[s][nf], acc[mi][2 + nf], 0, 0, 0);
    __builtin_amdgcn_s_setprio(0);
    FENCED_BARRIER();
  }

#pragma unroll
  for (int mi = 0; mi < 4; mi++)
#pragma unroll
    for (int nf = 0; nf < 4; nf++) {
      const int gcol = col0 + wn * 64 + nf * 16 + l15;
      const float bc = bias[gcol];
#pragma unroll
      for (int r = 0; r < 4; r++) {
        const int grow = row0 + wm * 64 + mi * 16 + quad * 4 + r;
        outF[(size_t)grow * N + gcol] = acc[mi][nf][r] + bc + resid[(size_t)grow * N + gcol];
      }
    }
}

// ---------------- causal flash attention, operand-swapped, reg-blocked ----------------
// qkv: [NTOK][3072] bf16 (q|k|v), Q pre-scaled by QSCALE. y: [NTOK][1024] bf16.
// Round-4 changes: occupancy 4 blocks/CU; V prefetched 1 tile ahead in regs (counted
// vmcnt(4) keeps prefetch in flight across the barrier); defer-max (THR=8 log2-units);
// sm_scale folded into Q at prep; setprio around MFMA clusters.
__global__ __launch_bounds__(256, 4)
void attn(const us* __restrict__ qkv, us* __restrict__ y) {
  // magic-square qt mapping: each CU-coset of blocks gets equal total work
  static const signed char QTM[16] = {15,14,13,12, 10,11,8,9, 5,4,7,6, 0,1,2,3};
  const int bx = blockIdx.x;
  const int bh = bx & 63;
  const int qt = QTM[(bx >> 6) & 15];
  const int bb = bh >> 4, h = bh & 15;
  const int tid = threadIdx.x;
  const int wave = tid >> 6, lane = tid & 63;
  const int quad = lane >> 4, l15 = lane & 15;

  __shared__ us Ks[128 * 64];   // phys us off = row*64 + ((col8 ^ (row&7))<<3)
  __shared__ us Vt[64 * 132];   // V^T[d][key], us off = d*132 + key

  const size_t base = (size_t)bb * SEQ * 3072;
  const int q0 = qt * 128;

  // Q B-fragments for two 16-q groups (rows wave*32 + qg*16 + l15)
  b8 bqf[2][2];
#pragma unroll
  for (int qg = 0; qg < 2; qg++) {
    const us* qp = qkv + base + (size_t)(q0 + wave * 32 + qg * 16 + l15) * 3072 + h * 64 + quad * 8;
    bqf[qg][0] = *(const b8*)qp;
    bqf[qg][1] = *(const b8*)(qp + 32);
  }

  const f4 zf = {0.f, 0.f, 0.f, 0.f};
  f4 o[2][4];                       // [qg][dg]: O[q=quad*4+r][d=dg*16+l15]
  float mrow[2], lrow[2];
#pragma unroll
  for (int qg = 0; qg < 2; qg++) {
    mrow[qg] = -3.0e38f; lrow[qg] = 0.f;
#pragma unroll
    for (int dg = 0; dg < 4; dg++) o[qg][dg] = zf;
  }

  // K staging: wave stages rows wave*32..+31 in 4 DMA ops of 8 rows.
  const int klr = lane >> 3, klc = lane & 7;
  const us* kgbase = qkv + base + (size_t)(wave * 32 + klr) * 3072 + 1024 + h * 64 + ((klc ^ klr) << 3);
  // V staging: thread handles key pair (2*lane, 2*lane+1), d-octets wave*8 and 32+wave*8.
  const us* vgbase = qkv + base + (size_t)(2 * lane) * 3072 + 2048 + h * 64 + wave * 8;

  // prologue: prefetch V of tile 0 into registers
  float4 va0 = *(const float4*)(vgbase);
  float4 va1 = *(const float4*)(vgbase + 3072);
  float4 va2 = *(const float4*)(vgbase + 32);
  float4 va3 = *(const float4*)(vgbase + 3072 + 32);

  for (int kt = 0; kt <= qt; kt++) {
    const size_t koff = (size_t)kt * 128 * 3072;
    // --- stage K (async DMA, XOR-swizzled source) ---
#pragma unroll
    for (int op = 0; op < 4; op++)
      async16(&Ks[(wave * 32 + op * 8) * 64], kgbase + koff + (size_t)op * 8 * 3072);
    // --- write V^T from prefetched regs (conflict-free packed writes) ---
    {
      union { float4 f; us u[8]; } v0, v1, v2, v3;
      v0.f = va0; v1.f = va1; v2.f = va2; v3.f = va3;
#pragma unroll
      for (int j = 0; j < 8; j++) {
        *(uint32_t*)&Vt[(wave * 8 + j) * 132 + 2 * lane] =
            (uint32_t)v0.u[j] | ((uint32_t)v1.u[j] << 16);
        *(uint32_t*)&Vt[(32 + wave * 8 + j) * 132 + 2 * lane] =
            (uint32_t)v2.u[j] | ((uint32_t)v3.u[j] << 16);
      }
    }
    // --- prefetch next tile's V; counted vmcnt leaves it in flight across barrier ---
    float4 vb0, vb1, vb2, vb3;
    if (kt < qt) {
      const us* vg = vgbase + koff + (size_t)128 * 3072;
      vb0 = *(const float4*)(vg);
      vb1 = *(const float4*)(vg + 3072);
      vb2 = *(const float4*)(vg + 32);
      vb3 = *(const float4*)(vg + 3072 + 32);
      asm volatile("s_waitcnt vmcnt(4)" ::: "memory");   // K DMA landed; V prefetch in flight
    } else {
      asm volatile("s_waitcnt vmcnt(0)" ::: "memory");   // K DMA landed
    }
    asm volatile("s_waitcnt lgkmcnt(0)" ::: "memory");   // Vt writes visible
    FENCED_BARRIER();

    // --- S^T = K·Q^T : sacc[qg][c] holds S^T[key=c*16+quad*4+r][q=l15] ---
    f4 sacc[2][8];
    __builtin_amdgcn_s_setprio(1);
#pragma unroll
    for (int c = 0; c < 8; c++) {
      const int krow = (c * 16 + l15) * 64;
      const int sw = l15 & 7;
      const b8 ak0 = *(const b8*)&Ks[krow + ((quad ^ sw) << 3)];
      const b8 ak1 = *(const b8*)&Ks[krow + (((quad ^ 4) ^ sw) << 3)];
#pragma unroll
      for (int qg = 0; qg < 2; qg++) {
        f4 s = __builtin_amdgcn_mfma_f32_16x16x32_bf16(ak0, bqf[qg][0], zf, 0, 0, 0);
        sacc[qg][c] = __builtin_amdgcn_mfma_f32_16x16x32_bf16(ak1, bqf[qg][1], s, 0, 0, 0);
      }
    }
    __builtin_amdgcn_s_setprio(0);

    // --- softmax per q-group (scores already in log2 units; defer-max THR=8) ---
    uint32_t pf[2][16];
#pragma unroll
    for (int qg = 0; qg < 2; qg++) {
      const int q_in = wave * 32 + qg * 16 + l15;
      if (kt == qt) {
#pragma unroll
        for (int c = 0; c < 8; c++)
#pragma unroll
          for (int r = 0; r < 4; r++)
            if ((c * 16 + quad * 4 + r) > q_in) sacc[qg][c][r] = -3.0e38f;
      }
      float mx = sacc[qg][0][0];
#pragma unroll
      for (int c = 0; c < 8; c++)
#pragma unroll
        for (int r = 0; r < 4; r++) mx = fmaxf(mx, sacc[qg][c][r]);
      mx = fmaxf(mx, __shfl_xor(mx, 16, 64));
      mx = fmaxf(mx, __shfl_xor(mx, 32, 64));
      if (!__all(mx - mrow[qg] <= 8.f)) {   // wave-uniform; P bounded by 2^8 when deferred
        const float mnew = fmaxf(mrow[qg], mx);
        const float al = __builtin_amdgcn_exp2f(mrow[qg] - mnew);
        mrow[qg] = mnew;
        lrow[qg] *= al;
#pragma unroll
        for (int r = 0; r < 4; r++) {
          const float ar = __shfl(al, quad * 4 + r, 64);
#pragma unroll
          for (int dg = 0; dg < 4; dg++) o[qg][dg][r] *= ar;
        }
      }
      const float mb = mrow[qg];
      float rs = 0.f;
#pragma unroll
      for (int c = 0; c < 8; c++) {
        const float p0 = __builtin_amdgcn_exp2f(sacc[qg][c][0] - mb);
        const float p1 = __builtin_amdgcn_exp2f(sacc[qg][c][1] - mb);
        const float p2 = __builtin_amdgcn_exp2f(sacc[qg][c][2] - mb);
        const float p3 = __builtin_amdgcn_exp2f(sacc[qg][c][3] - mb);
        rs += (p0 + p1) + (p2 + p3);
        pf[qg][c * 2] = pkbf(p0, p1);
        pf[qg][c * 2 + 1] = pkbf(p2, p3);
      }
      rs += __shfl_xor(rs, 16, 64);
      rs += __shfl_xor(rs, 32, 64);
      lrow[qg] += rs;
    }

    // --- O += P·V : V b64 reads shared across q-groups; zero-padded halves ---
    __builtin_amdgcn_s_setprio(1);
#pragma unroll
    for (int c = 0; c < 8; c++) {
      union { uint32_t w[4]; b8 v; } af0, af1;
      af0.w[0] = pf[0][c * 2]; af0.w[1] = pf[0][c * 2 + 1]; af0.w[2] = 0u; af0.w[3] = 0u;
      af1.w[0] = pf[1][c * 2]; af1.w[1] = pf[1][c * 2 + 1]; af1.w[2] = 0u; af1.w[3] = 0u;
#pragma unroll
      for (int dg = 0; dg < 4; dg++) {
        const uint2 vd = *(const uint2*)&Vt[(dg * 16 + l15) * 132 + c * 16 + quad * 4];
        union { uint32_t w[4]; b8 v; } vb;
        vb.w[0] = vd.x; vb.w[1] = vd.y; vb.w[2] = 0u; vb.w[3] = 0u;
        o[0][dg] = __builtin_amdgcn_mfma_f32_16x16x32_bf16(af0.v, vb.v, o[0][dg], 0, 0, 0);
        o[1][dg] = __builtin_amdgcn_mfma_f32_16x16x32_bf16(af1.v, vb.v, o[1][dg], 0, 0, 0);
      }
    }
    __builtin_amdgcn_s_setprio(0);
    asm volatile("s_waitcnt lgkmcnt(0)" ::: "memory");
    FENCED_BARRIER();   // before next tile overwrites Ks/Vt
    if (kt < qt) {      // hand prefetched V to next iteration (vmcnt wait lands here, hidden)
      va0 = vb0; va1 = vb1; va2 = vb2; va3 = vb3;
    }
  }

#pragma unroll
  for (int qg = 0; qg < 2; qg++) {
    float lr[4];
#pragma unroll
    for (int r = 0; r < 4; r++) lr[r] = __shfl(lrow[qg], quad * 4 + r, 64);
#pragma unroll
    for (int dg = 0; dg < 4; dg++)
#pragma unroll
      for (int r = 0; r < 4; r++) {
        const int gq = q0 + wave * 32 + qg * 16 + quad * 4 + r;
        y[(size_t)(bb * SEQ + gq) * EMB + h * 64 + dg * 16 + l15] = f2b(o[qg][dg][r] / lr[r]);
      }
  }
}

extern "C" void kernel_launch(void* const* d_in, const int* in_sizes, int n_in,
                              void* d_out, int out_size, void* d_ws, size_t ws_size,
                              hipStream_t stream) {
  const float* x = (const float*)d_in[0];
  const float* Wq = (const float*)d_in[1];
  const float* bq = (const float*)d_in[2];
  const float* Wk = (const float*)d_in[3];
  const float* bk = (const float*)d_in[4];
  const float* Wv = (const float*)d_in[5];
  const float* bv = (const float*)d_in[6];
  const float* Wo = (const float*)d_in[7];
  const float* bo = (const float*)d_in[8];
  const float* g1 = (const float*)d_in[9];
  const float* be1 = (const float*)d_in[10];
  const float* g2 = (const float*)d_in[11];
  const float* be2 = (const float*)d_in[12];
  const float* W1 = (const float*)d_in[13];
  const float* b1 = (const float*)d_in[14];
  const float* W2 = (const float*)d_in[15];
  const float* b2 = (const float*)d_in[16];
  float* out = (float*)d_out;

  char* ws = (char*)d_ws;
  const size_t MB = 1024ull * 1024ull;
  us* WqkvT = (us*)(ws + 0);          // [3072][1024] bf16
  us* WoT   = (us*)(ws + 6 * MB);     // [1024][1024]
  us* W1T   = (us*)(ws + 8 * MB);     // [4096][1024]
  us* W2T   = (us*)(ws + 16 * MB);    // [1024][4096]
  us* hbuf  = (us*)(ws + 24 * MB);    // [8192][1024] bf16 (LN1 out)
  us* qkvb  = (us*)(ws + 40 * MB);    // [8192][3072] bf16
  us* ybuf  = (us*)(ws + 88 * MB);    // [8192][1024] bf16
  float* x1 = (float*)(ws + 104 * MB);// [8192][1024] f32
  us* h2    = (us*)(ws + 136 * MB);   // [8192][1024] bf16
  us* ff1   = (us*)(ws + 24 * MB);    // [8192][4096] bf16 (reuses h/qkv region)
  float* bqkv = (float*)(ws + 152 * MB); // [3072] f32

  transpose_cast<<<dim3(32, 32), 256, 0, stream>>>(Wq, WqkvT, 1024, 1024, QSCALE);
  transpose_cast<<<dim3(32, 32), 256, 0, stream>>>(Wk, WqkvT + 1024 * 1024, 1024, 1024, 1.f);
  transpose_cast<<<dim3(32, 32), 256, 0, stream>>>(Wv, WqkvT + 2 * 1024 * 1024, 1024, 1024, 1.f);
  transpose_cast<<<dim3(32, 32), 256, 0, stream>>>(Wo, WoT, 1024, 1024, 1.f);
  transpose_cast<<<dim3(128, 32), 256, 0, stream>>>(W1, W1T, 1024, 4096, 1.f);
  transpose_cast<<<dim3(32, 128), 256, 0, stream>>>(W2, W2T, 4096, 1024, 1.f);
  pack_bias<<<12, 256, 0, stream>>>(bq, bk, bv, bqkv);

  ln_kernel<<<NTOK, 256, 0, stream>>>(x, g1, be1, hbuf);
  // QKV: M=8192 N=3072 K=1024 -> 32x12 = 384 blocks, BM=256 BN=256
  gemm256<<<dim3(384), 512, 0, stream>>>(hbuf, WqkvT, bqkv, qkvb, 3072, 1024, 0, 12);
  attn<<<1024, 256, 0, stream>>>(qkvb, ybuf);
  // proj: M=8192 N=1024 K=1024 -> 64x4 = 256 blocks, BM=128 BN=256, resid=x -> x1
  gemm128<<<dim3(256), 512, 0, stream>>>(ybuf, WoT, bo, x, x1, 1024, 1024, 4);
  ln_kernel<<<NTOK, 256, 0, stream>>>(x1, g2, be2, h2);
  // FF1: M=8192 N=4096 K=1024 -> 32x16 = 512 blocks, gelu
  gemm256<<<dim3(512), 512, 0, stream>>>(h2, W1T, b1, ff1, 4096, 1024, 1, 16);
  // FF2: M=8192 N=1024 K=4096 -> 64x4 = 256 blocks, resid=x1 -> out
  gemm128<<<dim3(256), 512, 0, stream>>>(ff1, W2T, b2, x1, out, 1024, 4096, 4);
}

// Round 5
// 519.697 us; speedup vs baseline: 1.2086x; 1.2086x over previous
//
#include <hip/hip_runtime.h>
#include <hip/hip_bf16.h>
#include <stdint.h>
#include <math.h>

#define SEQ 2048
#define NTOK 8192        // B*S
#define EMB 1024
#define NH 16
#define HD 64
#define FFD 4096
#define QSCALE 0.1803368801111137f   // 0.125 * log2(e), folded into Wq/bq

using us = unsigned short;
using b8 = __attribute__((ext_vector_type(8))) __bf16;
using f4 = __attribute__((ext_vector_type(4))) float;

__device__ __forceinline__ us f2b(float f) {
  union { float f; uint32_t u; } v; v.f = f;
  uint32_t u = v.u;
  return (us)((u + 0x7fffu + ((u >> 16) & 1u)) >> 16);  // RNE
}

// pack two fp32 -> bf16x2 (round-half-up; P >= 0, bias negligible)
__device__ __forceinline__ uint32_t pkbf(float a, float b) {
  union { float f; uint32_t u; } x, y; x.f = a; y.f = b;
  return ((x.u + 0x8000u) >> 16) | ((y.u + 0x8000u) & 0xFFFF0000u);
}

__device__ __forceinline__ void async16(void* lds, const void* g) {
  __builtin_amdgcn_global_load_lds(
      (__attribute__((address_space(1))) void*)(uintptr_t)g,
      (__attribute__((address_space(3))) void*)(uintptr_t)lds, 16, 0, 0);
}

#define FENCED_BARRIER() do { asm volatile("" ::: "memory"); \
  __builtin_amdgcn_s_barrier(); asm volatile("" ::: "memory"); } while (0)

// tanh-form GELU: 0.5x(1+tanh(k0(x+k1 x^3))) = x*sigmoid(2 k0 (x+k1 x^3))
// |err vs exact erf-gelu| < ~1e-3, below ff1's bf16 quantization.
__device__ __forceinline__ float gelu_f(float x) {
  const float z = -2.30211416f * x * (1.f + 0.044715f * x * x);
  return x / (1.f + __builtin_amdgcn_exp2f(z));
}

// ---------------- transpose + cast (+scale): in [R][C] f32 -> out [C][R] bf16 ----------------
__global__ __launch_bounds__(256)
void transpose_cast(const float* __restrict__ in, us* __restrict__ out, int R, int C,
                    float scale) {
  __shared__ float tile[32][33];
  const int bc = blockIdx.x * 32, br = blockIdx.y * 32;
  const int tx = threadIdx.x & 31, ty = threadIdx.x >> 5;
#pragma unroll
  for (int i = 0; i < 32; i += 8)
    tile[ty + i][tx] = in[(size_t)(br + ty + i) * C + bc + tx];
  __syncthreads();
#pragma unroll
  for (int i = 0; i < 32; i += 8)
    out[(size_t)(bc + ty + i) * R + br + tx] = f2b(tile[tx][ty + i] * scale);
}

// ---------------- pack bq|bk|bv into one [3072]; bq pre-scaled by QSCALE ----------------
__global__ void pack_bias(const float* __restrict__ bq, const float* __restrict__ bk,
                          const float* __restrict__ bv, float* __restrict__ o) {
  int i = blockIdx.x * 256 + threadIdx.x;
  o[i] = (i < 1024) ? bq[i] * QSCALE : (i < 2048 ? bk[i - 1024] : bv[i - 2048]);
}

// ---------------- LayerNorm: fp32 in -> bf16 out, one block per token ----------------
__global__ __launch_bounds__(256)
void ln_kernel(const float* __restrict__ x, const float* __restrict__ g,
               const float* __restrict__ be, us* __restrict__ out) {
  __shared__ float red[8];
  const int row = blockIdx.x, t = threadIdx.x;
  const float4 v = ((const float4*)(x + (size_t)row * EMB))[t];
  float s = v.x + v.y + v.z + v.w;
  float s2 = v.x * v.x + v.y * v.y + v.z * v.z + v.w * v.w;
#pragma unroll
  for (int o = 32; o; o >>= 1) { s += __shfl_down(s, o, 64); s2 += __shfl_down(s2, o, 64); }
  if ((t & 63) == 0) { red[(t >> 6) * 2] = s; red[(t >> 6) * 2 + 1] = s2; }
  __syncthreads();
  const float ts = red[0] + red[2] + red[4] + red[6];
  const float ts2 = red[1] + red[3] + red[5] + red[7];
  const float mu = ts * (1.f / 1024.f);
  const float rs = rsqrtf(ts2 * (1.f / 1024.f) - mu * mu + 1e-5f);
  const float4 gv = ((const float4*)g)[t];
  const float4 bv = ((const float4*)be)[t];
  ushort4 o4;
  o4.x = f2b((v.x - mu) * rs * gv.x + bv.x);
  o4.y = f2b((v.y - mu) * rs * gv.y + bv.y);
  o4.z = f2b((v.z - mu) * rs * gv.z + bv.z);
  o4.w = f2b((v.w - mu) * rs * gv.w + bv.w);
  ((ushort4*)(out + (size_t)row * EMB))[t] = o4;
}

// ================= 8-phase GEMM, BM=256 x BN=256, BK=64, 8 waves (2M x 4N) =================
// (unchanged from round 3 -- vmcnt(6) counted pipeline, T2 XOR swizzle, T5 setprio)
__global__ __launch_bounds__(512, 2)
void gemm256(const us* __restrict__ A, const us* __restrict__ Bt,
             const float* __restrict__ bias, us* __restrict__ outB,
             int N, int K, int gelu, int gy) {
  __shared__ us As[2][256 * 64];   // 64 KB
  __shared__ us Bs[2][256 * 64];   // 64 KB

  int bid = blockIdx.x;
  const int cpx = (int)gridDim.x >> 3;         // grid % 8 == 0 always here
  bid = (bid & 7) * cpx + (bid >> 3);          // bijective XCD swizzle
  const int bx = bid / gy, by = bid - bx * gy;
  const int row0 = bx * 256, col0 = by * 256;

  const int tid = threadIdx.x, w = tid >> 6, lane = tid & 63;
  const int wm = w >> 2, wn = w & 3;
  const int quad = lane >> 4, l15 = lane & 15;
  const int xr = l15 & 7;

  const int u0 = w * 2, u1 = u0 + 1;
  const int ar0 = ((u0 & 7) << 3) + ((u0 >> 3) << 7);   // A: {0..56} + {0,128}
  const int ar1 = ((u1 & 7) << 3) + ((u1 >> 3) << 7);
  const int br0 = ((u0 & 3) << 3) + ((u0 >> 2) << 6);   // B: {0..24} + {0,64,128,192}
  const int br1 = ((u1 & 3) << 3) + ((u1 >> 2) << 6);
  const int lrow = lane >> 3;
  const int loct = ((lane & 7) ^ lrow) << 3;            // inverse-swizzled source octet
  const us* Ag0 = A + (size_t)(row0 + ar0 + lrow) * K + loct;
  const us* Ag1 = A + (size_t)(row0 + ar1 + lrow) * K + loct;
  const us* Bg0 = Bt + (size_t)(col0 + br0 + lrow) * K + loct;
  const us* Bg1 = Bt + (size_t)(col0 + br1 + lrow) * K + loct;
  const int NT = K >> 6;

  const f4 zf = {0.f, 0.f, 0.f, 0.f};
  f4 acc[8][4];
#pragma unroll
  for (int i = 0; i < 8; i++)
#pragma unroll
    for (int j = 0; j < 4; j++) acc[i][j] = zf;

  auto stgA = [&](int buf, int t, int mh) {
    const size_t go = (size_t)(mh << 6) * K + ((size_t)t << 6);
    async16(&As[buf][(ar0 + (mh << 6)) << 6], Ag0 + go);
    async16(&As[buf][(ar1 + (mh << 6)) << 6], Ag1 + go);
  };
  auto stgB = [&](int buf, int t, int nh) {
    const size_t go = (size_t)(nh << 5) * K + ((size_t)t << 6);
    async16(&Bs[buf][(br0 + (nh << 5)) << 6], Bg0 + go);
    async16(&Bs[buf][(br1 + (nh << 5)) << 6], Bg1 + go);
  };

  stgA(0, 0, 0); stgB(0, 0, 0); stgB(0, 0, 1); stgA(0, 0, 1);
  stgA(1, 1, 0); stgB(1, 1, 0); stgB(1, 1, 1);
  asm volatile("s_waitcnt vmcnt(6)" ::: "memory");
  FENCED_BARRIER();

  for (int t = 0; t < NT; t++) {
    const int cur = t & 1, nxt = cur ^ 1;
    const us* __restrict__ as = As[cur];
    const us* __restrict__ bs = Bs[cur];
    b8 af[2][4], bf0[2][2], bf1[2][2];

    // ---- phase 1 (mh0, nh0): 12 ds_reads, stage U4(t+1)
#pragma unroll
    for (int s = 0; s < 2; s++) {
      const int po = (((s << 2) + quad) ^ xr) << 3;
#pragma unroll
      for (int mi = 0; mi < 4; mi++)
        af[s][mi] = *(const b8*)&as[(wm * 128 + mi * 16 + l15) * 64 + po];
#pragma unroll
      for (int nf = 0; nf < 2; nf++)
        bf0[s][nf] = *(const b8*)&bs[(wn * 64 + nf * 16 + l15) * 64 + po];
    }
    if (t + 1 < NT) stgA(nxt, t + 1, 1);
    FENCED_BARRIER();
    asm volatile("s_waitcnt lgkmcnt(0)" ::: "memory");
    __builtin_amdgcn_s_setprio(1);
#pragma unroll
    for (int s = 0; s < 2; s++)
#pragma unroll
      for (int mi = 0; mi < 4; mi++)
#pragma unroll
        for (int nf = 0; nf < 2; nf++)
          acc[mi][nf] = __builtin_amdgcn_mfma_f32_16x16x32_bf16(af[s][mi], bf0[s][nf], acc[mi][nf], 0, 0, 0);
    __builtin_amdgcn_s_setprio(0);
    FENCED_BARRIER();

    // ---- phase 2 (mh0, nh1): 4 ds_reads, stage U1(t+2)
#pragma unroll
    for (int s = 0; s < 2; s++) {
      const int po = (((s << 2) + quad) ^ xr) << 3;
#pragma unroll
      for (int nf = 0; nf < 2; nf++)
        bf1[s][nf] = *(const b8*)&bs[(wn * 64 + 32 + nf * 16 + l15) * 64 + po];
    }
    if (t + 2 < NT) stgA(cur, t + 2, 0);
    FENCED_BARRIER();
    asm volatile("s_waitcnt lgkmcnt(0)" ::: "memory");
    __builtin_amdgcn_s_setprio(1);
#pragma unroll
    for (int s = 0; s < 2; s++)
#pragma unroll
      for (int mi = 0; mi < 4; mi++)
#pragma unroll
        for (int nf = 0; nf < 2; nf++)
          acc[mi][2 + nf] = __builtin_amdgcn_mfma_f32_16x16x32_bf16(af[s][mi], bf1[s][nf], acc[mi][2 + nf], 0, 0, 0);
    __builtin_amdgcn_s_setprio(0);
    FENCED_BARRIER();

    // ---- phase 3 (mh1, nh0): 8 ds_reads, stage U2(t+2)
#pragma unroll
    for (int s = 0; s < 2; s++) {
      const int po = (((s << 2) + quad) ^ xr) << 3;
#pragma unroll
      for (int mi = 0; mi < 4; mi++)
        af[s][mi] = *(const b8*)&as[(wm * 128 + 64 + mi * 16 + l15) * 64 + po];
    }
    if (t + 2 < NT) stgB(cur, t + 2, 0);
    FENCED_BARRIER();
    asm volatile("s_waitcnt lgkmcnt(0)" ::: "memory");
    __builtin_amdgcn_s_setprio(1);
#pragma unroll
    for (int s = 0; s < 2; s++)
#pragma unroll
      for (int mi = 0; mi < 4; mi++)
#pragma unroll
        for (int nf = 0; nf < 2; nf++)
          acc[4 + mi][nf] = __builtin_amdgcn_mfma_f32_16x16x32_bf16(af[s][mi], bf0[s][nf], acc[4 + mi][nf], 0, 0, 0);
    __builtin_amdgcn_s_setprio(0);
    FENCED_BARRIER();

    // ---- phase 4 (mh1, nh1): 0 ds_reads, stage U3(t+2), once-per-tile vmcnt
    if (t + 2 < NT) {
      stgB(cur, t + 2, 1);
      asm volatile("s_waitcnt vmcnt(6)" ::: "memory");   // retires all of tile t+1
    } else {
      asm volatile("s_waitcnt vmcnt(0)" ::: "memory");
    }
    FENCED_BARRIER();
    __builtin_amdgcn_s_setprio(1);
#pragma unroll
    for (int s = 0; s < 2; s++)
#pragma unroll
      for (int mi = 0; mi < 4; mi++)
#pragma unroll
        for (int nf = 0; nf < 2; nf++)
          acc[4 + mi][2 + nf] = __builtin_amdgcn_mfma_f32_16x16x32_bf16(af[s][mi], bf1[s][nf], acc[4 + mi][2 + nf], 0, 0, 0);
    __builtin_amdgcn_s_setprio(0);
    FENCED_BARRIER();
  }

#pragma unroll
  for (int mi8 = 0; mi8 < 8; mi8++)
#pragma unroll
    for (int nf = 0; nf < 4; nf++) {
      const int gcol = col0 + wn * 64 + nf * 16 + l15;
      const float bc = bias[gcol];
#pragma unroll
      for (int r = 0; r < 4; r++) {
        const int grow = row0 + wm * 128 + mi8 * 16 + quad * 4 + r;
        float v = acc[mi8][nf][r] + bc;
        if (gelu) v = gelu_f(v);
        outB[(size_t)grow * N + gcol] = f2b(v);
      }
    }
}

// ================= 8-phase GEMM, BM=128 x BN=256 (f32 out + resid) ==================
// (unchanged from round 3)
__global__ __launch_bounds__(512, 2)
void gemm128(const us* __restrict__ A, const us* __restrict__ Bt,
             const float* __restrict__ bias, const float* __restrict__ resid,
             float* __restrict__ outF, int N, int K, int gy) {
  __shared__ us As[2][128 * 64];   // 32 KB
  __shared__ us Bs[2][256 * 64];   // 64 KB

  int bid = blockIdx.x;
  const int cpx = (int)gridDim.x >> 3;
  bid = (bid & 7) * cpx + (bid >> 3);
  const int bx = bid / gy, by = bid - bx * gy;
  const int row0 = bx * 128, col0 = by * 256;

  const int tid = threadIdx.x, w = tid >> 6, lane = tid & 63;
  const int wm = w >> 2, wn = w & 3;
  const int quad = lane >> 4, l15 = lane & 15;
  const int xr = l15 & 7;

  const int u0 = w * 2, u1 = u0 + 1;
  const int aR0 = u0 << 3, aR1 = u1 << 3;               // A rows 0..127
  const int bR0 = ((u0 & 3) << 3) + ((u0 >> 2) << 6);
  const int bR1 = ((u1 & 3) << 3) + ((u1 >> 2) << 6);
  const int lrow = lane >> 3;
  const int loct = ((lane & 7) ^ lrow) << 3;
  const us* Ag0 = A + (size_t)(row0 + aR0 + lrow) * K + loct;
  const us* Ag1 = A + (size_t)(row0 + aR1 + lrow) * K + loct;
  const us* Bg0 = Bt + (size_t)(col0 + bR0 + lrow) * K + loct;
  const us* Bg1 = Bt + (size_t)(col0 + bR1 + lrow) * K + loct;
  const int NT = K >> 6;

  const f4 zf = {0.f, 0.f, 0.f, 0.f};
  f4 acc[4][4];
#pragma unroll
  for (int i = 0; i < 4; i++)
#pragma unroll
    for (int j = 0; j < 4; j++) acc[i][j] = zf;

  auto stgA = [&](int buf, int t) {
    const size_t go = (size_t)t << 6;
    async16(&As[buf][aR0 << 6], Ag0 + go);
    async16(&As[buf][aR1 << 6], Ag1 + go);
  };
  auto stgB = [&](int buf, int t, int nh) {
    const size_t go = (size_t)(nh << 5) * K + ((size_t)t << 6);
    async16(&Bs[buf][(bR0 + (nh << 5)) << 6], Bg0 + go);
    async16(&Bs[buf][(bR1 + (nh << 5)) << 6], Bg1 + go);
  };

  stgA(0, 0); stgB(0, 0, 0); stgB(0, 0, 1);
  stgA(1, 1); stgB(1, 1, 0);
  asm volatile("s_waitcnt vmcnt(6)" ::: "memory");
  FENCED_BARRIER();

  for (int t = 0; t < NT; t++) {
    const int cur = t & 1, nxt = cur ^ 1;
    const us* __restrict__ as = As[cur];
    const us* __restrict__ bs = Bs[cur];
    b8 af[2][4], bf0[2][2], bf1[2][2];

    // ---- phase 1: 12 ds_reads, stage UB1(t+1), retire UB1(t)
#pragma unroll
    for (int s = 0; s < 2; s++) {
      const int po = (((s << 2) + quad) ^ xr) << 3;
#pragma unroll
      for (int mi = 0; mi < 4; mi++)
        af[s][mi] = *(const b8*)&as[(wm * 64 + mi * 16 + l15) * 64 + po];
#pragma unroll
      for (int nf = 0; nf < 2; nf++)
        bf0[s][nf] = *(const b8*)&bs[(wn * 64 + nf * 16 + l15) * 64 + po];
    }
    if (t + 1 < NT) {
      stgB(nxt, t + 1, 1);
      asm volatile("s_waitcnt vmcnt(6)" ::: "memory");
    } else {
      asm volatile("s_waitcnt vmcnt(0)" ::: "memory");
    }
    FENCED_BARRIER();
    asm volatile("s_waitcnt lgkmcnt(0)" ::: "memory");
    __builtin_amdgcn_s_setprio(1);
#pragma unroll
    for (int s = 0; s < 2; s++)
#pragma unroll
      for (int mi = 0; mi < 4; mi++)
#pragma unroll
        for (int nf = 0; nf < 2; nf++)
          acc[mi][nf] = __builtin_amdgcn_mfma_f32_16x16x32_bf16(af[s][mi], bf0[s][nf], acc[mi][nf], 0, 0, 0);
    __builtin_amdgcn_s_setprio(0);
    FENCED_BARRIER();

    // ---- phase 2: 4 ds_reads, stage UA(t+2)+UB0(t+2), retire UA,UB0(t+1)
#pragma unroll
    for (int s = 0; s < 2; s++) {
      const int po = (((s << 2) + quad) ^ xr) << 3;
#pragma unroll
      for (int nf = 0; nf < 2; nf++)
        bf1[s][nf] = *(const b8*)&bs[(wn * 64 + 32 + nf * 16 + l15) * 64 + po];
    }
    if (t + 2 < NT) {
      stgA(cur, t + 2); stgB(cur, t + 2, 0);
      asm volatile("s_waitcnt vmcnt(6)" ::: "memory");
    } else {
      asm volatile("s_waitcnt vmcnt(2)" ::: "memory");
    }
    FENCED_BARRIER();
    asm volatile("s_waitcnt lgkmcnt(0)" ::: "memory");
    __builtin_amdgcn_s_setprio(1);
#pragma unroll
    for (int s = 0; s < 2; s++)
#pragma unroll
      for (int mi = 0; mi < 4; mi++)
#pragma unroll
        for (int nf = 0; nf < 2; nf++)
          acc[mi][2 + nf] = __builtin_amdgcn_mfma_f32_16x16x32_bf16(af[s][mi], bf1[s][nf], acc[mi][2 + nf], 0, 0, 0);
    __builtin_amdgcn_s_setprio(0);
    FENCED_BARRIER();
  }

#pragma unroll
  for (int mi = 0; mi < 4; mi++)
#pragma unroll
    for (int nf = 0; nf < 4; nf++) {
      const int gcol = col0 + wn * 64 + nf * 16 + l15;
      const float bc = bias[gcol];
#pragma unroll
      for (int r = 0; r < 4; r++) {
        const int grow = row0 + wm * 64 + mi * 16 + quad * 4 + r;
        outF[(size_t)grow * N + gcol] = acc[mi][nf][r] + bc + resid[(size_t)grow * N + gcol];
      }
    }
}

// ---------------- causal flash attention, operand-swapped, reg-blocked ----------------
// qkv: [NTOK][3072] bf16 (q|k|v), Q pre-scaled by QSCALE. y: [NTOK][1024] bf16.
// launch_bounds(256,3): round-4's (256,4) capped VGPR at 64 -> massive scratch spill
// (WRITE_SIZE 433 MB vs 34 MB legit). At 3 waves/EU the ~116-VGPR body fits, no spill.
// V prefetched 1 tile ahead in regs (counted vmcnt(4) keeps it in flight across the
// barrier); defer-max THR=8; sm_scale folded into Q at prep; setprio on MFMA clusters.
__global__ __launch_bounds__(256, 3)
void attn(const us* __restrict__ qkv, us* __restrict__ y) {
  // magic-square qt mapping: each CU-coset of blocks gets equal total work
  static const signed char QTM[16] = {15,14,13,12, 10,11,8,9, 5,4,7,6, 0,1,2,3};
  const int bx = blockIdx.x;
  const int bh = bx & 63;
  const int qt = QTM[(bx >> 6) & 15];
  const int bb = bh >> 4, h = bh & 15;
  const int tid = threadIdx.x;
  const int wave = tid >> 6, lane = tid & 63;
  const int quad = lane >> 4, l15 = lane & 15;

  __shared__ us Ks[128 * 64];   // phys us off = row*64 + ((col8 ^ (row&7))<<3)
  __shared__ us Vt[64 * 132];   // V^T[d][key], us off = d*132 + key

  const size_t base = (size_t)bb * SEQ * 3072;
  const int q0 = qt * 128;

  // Q B-fragments for two 16-q groups (rows wave*32 + qg*16 + l15)
  b8 bqf[2][2];
#pragma unroll
  for (int qg = 0; qg < 2; qg++) {
    const us* qp = qkv + base + (size_t)(q0 + wave * 32 + qg * 16 + l15) * 3072 + h * 64 + quad * 8;
    bqf[qg][0] = *(const b8*)qp;
    bqf[qg][1] = *(const b8*)(qp + 32);
  }

  const f4 zf = {0.f, 0.f, 0.f, 0.f};
  f4 o[2][4];                       // [qg][dg]: O[q=quad*4+r][d=dg*16+l15]
  float mrow[2], lrow[2];
#pragma unroll
  for (int qg = 0; qg < 2; qg++) {
    mrow[qg] = -3.0e38f; lrow[qg] = 0.f;
#pragma unroll
    for (int dg = 0; dg < 4; dg++) o[qg][dg] = zf;
  }

  // K staging: wave stages rows wave*32..+31 in 4 DMA ops of 8 rows.
  const int klr = lane >> 3, klc = lane & 7;
  const us* kgbase = qkv + base + (size_t)(wave * 32 + klr) * 3072 + 1024 + h * 64 + ((klc ^ klr) << 3);
  // V staging: thread handles key pair (2*lane, 2*lane+1), d-octets wave*8 and 32+wave*8.
  const us* vgbase = qkv + base + (size_t)(2 * lane) * 3072 + 2048 + h * 64 + wave * 8;

  // prologue: prefetch V of tile 0 into registers
  float4 va0 = *(const float4*)(vgbase);
  float4 va1 = *(const float4*)(vgbase + 3072);
  float4 va2 = *(const float4*)(vgbase + 32);
  float4 va3 = *(const float4*)(vgbase + 3072 + 32);

  for (int kt = 0; kt <= qt; kt++) {
    const size_t koff = (size_t)kt * 128 * 3072;
    // --- stage K (async DMA, XOR-swizzled source) ---
#pragma unroll
    for (int op = 0; op < 4; op++)
      async16(&Ks[(wave * 32 + op * 8) * 64], kgbase + koff + (size_t)op * 8 * 3072);
    // --- write V^T from prefetched regs (conflict-free packed writes) ---
    {
      union { float4 f; us u[8]; } v0, v1, v2, v3;
      v0.f = va0; v1.f = va1; v2.f = va2; v3.f = va3;
#pragma unroll
      for (int j = 0; j < 8; j++) {
        *(uint32_t*)&Vt[(wave * 8 + j) * 132 + 2 * lane] =
            (uint32_t)v0.u[j] | ((uint32_t)v1.u[j] << 16);
        *(uint32_t*)&Vt[(32 + wave * 8 + j) * 132 + 2 * lane] =
            (uint32_t)v2.u[j] | ((uint32_t)v3.u[j] << 16);
      }
    }
    // --- prefetch next tile's V; counted vmcnt leaves it in flight across barrier ---
    float4 vb0, vb1, vb2, vb3;
    if (kt < qt) {
      const us* vg = vgbase + koff + (size_t)128 * 3072;
      vb0 = *(const float4*)(vg);
      vb1 = *(const float4*)(vg + 3072);
      vb2 = *(const float4*)(vg + 32);
      vb3 = *(const float4*)(vg + 3072 + 32);
      asm volatile("s_waitcnt vmcnt(4)" ::: "memory");   // K DMA landed; V prefetch in flight
    } else {
      asm volatile("s_waitcnt vmcnt(0)" ::: "memory");   // K DMA landed
    }
    asm volatile("s_waitcnt lgkmcnt(0)" ::: "memory");   // Vt writes visible
    FENCED_BARRIER();

    // --- S^T = K·Q^T : sacc[qg][c] holds S^T[key=c*16+quad*4+r][q=l15] ---
    f4 sacc[2][8];
    __builtin_amdgcn_s_setprio(1);
#pragma unroll
    for (int c = 0; c < 8; c++) {
      const int krow = (c * 16 + l15) * 64;
      const int sw = l15 & 7;
      const b8 ak0 = *(const b8*)&Ks[krow + ((quad ^ sw) << 3)];
      const b8 ak1 = *(const b8*)&Ks[krow + (((quad ^ 4) ^ sw) << 3)];
#pragma unroll
      for (int qg = 0; qg < 2; qg++) {
        f4 s = __builtin_amdgcn_mfma_f32_16x16x32_bf16(ak0, bqf[qg][0], zf, 0, 0, 0);
        sacc[qg][c] = __builtin_amdgcn_mfma_f32_16x16x32_bf16(ak1, bqf[qg][1], s, 0, 0, 0);
      }
    }
    __builtin_amdgcn_s_setprio(0);

    // --- softmax per q-group (scores already in log2 units; defer-max THR=8) ---
    uint32_t pf[2][16];
#pragma unroll
    for (int qg = 0; qg < 2; qg++) {
      const int q_in = wave * 32 + qg * 16 + l15;
      if (kt == qt) {
#pragma unroll
        for (int c = 0; c < 8; c++)
#pragma unroll
          for (int r = 0; r < 4; r++)
            if ((c * 16 + quad * 4 + r) > q_in) sacc[qg][c][r] = -3.0e38f;
      }
      float mx = sacc[qg][0][0];
#pragma unroll
      for (int c = 0; c < 8; c++)
#pragma unroll
        for (int r = 0; r < 4; r++) mx = fmaxf(mx, sacc[qg][c][r]);
      mx = fmaxf(mx, __shfl_xor(mx, 16, 64));
      mx = fmaxf(mx, __shfl_xor(mx, 32, 64));
      if (!__all(mx - mrow[qg] <= 8.f)) {   // wave-uniform; P bounded by 2^8 when deferred
        const float mnew = fmaxf(mrow[qg], mx);
        const float al = __builtin_amdgcn_exp2f(mrow[qg] - mnew);
        mrow[qg] = mnew;
        lrow[qg] *= al;
#pragma unroll
        for (int r = 0; r < 4; r++) {
          const float ar = __shfl(al, quad * 4 + r, 64);
#pragma unroll
          for (int dg = 0; dg < 4; dg++) o[qg][dg][r] *= ar;
        }
      }
      const float mb = mrow[qg];
      float rs = 0.f;
#pragma unroll
      for (int c = 0; c < 8; c++) {
        const float p0 = __builtin_amdgcn_exp2f(sacc[qg][c][0] - mb);
        const float p1 = __builtin_amdgcn_exp2f(sacc[qg][c][1] - mb);
        const float p2 = __builtin_amdgcn_exp2f(sacc[qg][c][2] - mb);
        const float p3 = __builtin_amdgcn_exp2f(sacc[qg][c][3] - mb);
        rs += (p0 + p1) + (p2 + p3);
        pf[qg][c * 2] = pkbf(p0, p1);
        pf[qg][c * 2 + 1] = pkbf(p2, p3);
      }
      rs += __shfl_xor(rs, 16, 64);
      rs += __shfl_xor(rs, 32, 64);
      lrow[qg] += rs;
    }

    // --- O += P·V : V b64 reads shared across q-groups; zero-padded halves ---
    __builtin_amdgcn_s_setprio(1);
#pragma unroll
    for (int c = 0; c < 8; c++) {
      union { uint32_t w[4]; b8 v; } af0, af1;
      af0.w[0] = pf[0][c * 2]; af0.w[1] = pf[0][c * 2 + 1]; af0.w[2] = 0u; af0.w[3] = 0u;
      af1.w[0] = pf[1][c * 2]; af1.w[1] = pf[1][c * 2 + 1]; af1.w[2] = 0u; af1.w[3] = 0u;
#pragma unroll
      for (int dg = 0; dg < 4; dg++) {
        const uint2 vd = *(const uint2*)&Vt[(dg * 16 + l15) * 132 + c * 16 + quad * 4];
        union { uint32_t w[4]; b8 v; } vb;
        vb.w[0] = vd.x; vb.w[1] = vd.y; vb.w[2] = 0u; vb.w[3] = 0u;
        o[0][dg] = __builtin_amdgcn_mfma_f32_16x16x32_bf16(af0.v, vb.v, o[0][dg], 0, 0, 0);
        o[1][dg] = __builtin_amdgcn_mfma_f32_16x16x32_bf16(af1.v, vb.v, o[1][dg], 0, 0, 0);
      }
    }
    __builtin_amdgcn_s_setprio(0);
    asm volatile("s_waitcnt lgkmcnt(0)" ::: "memory");
    FENCED_BARRIER();   // before next tile overwrites Ks/Vt
    if (kt < qt) {      // hand prefetched V to next iteration
      va0 = vb0; va1 = vb1; va2 = vb2; va3 = vb3;
    }
  }

#pragma unroll
  for (int qg = 0; qg < 2; qg++) {
    float lr[4];
#pragma unroll
    for (int r = 0; r < 4; r++) lr[r] = __shfl(lrow[qg], quad * 4 + r, 64);
#pragma unroll
    for (int dg = 0; dg < 4; dg++)
#pragma unroll
      for (int r = 0; r < 4; r++) {
        const int gq = q0 + wave * 32 + qg * 16 + quad * 4 + r;
        y[(size_t)(bb * SEQ + gq) * EMB + h * 64 + dg * 16 + l15] = f2b(o[qg][dg][r] / lr[r]);
      }
  }
}

extern "C" void kernel_launch(void* const* d_in, const int* in_sizes, int n_in,
                              void* d_out, int out_size, void* d_ws, size_t ws_size,
                              hipStream_t stream) {
  const float* x = (const float*)d_in[0];
  const float* Wq = (const float*)d_in[1];
  const float* bq = (const float*)d_in[2];
  const float* Wk = (const float*)d_in[3];
  const float* bk = (const float*)d_in[4];
  const float* Wv = (const float*)d_in[5];
  const float* bv = (const float*)d_in[6];
  const float* Wo = (const float*)d_in[7];
  const float* bo = (const float*)d_in[8];
  const float* g1 = (const float*)d_in[9];
  const float* be1 = (const float*)d_in[10];
  const float* g2 = (const float*)d_in[11];
  const float* be2 = (const float*)d_in[12];
  const float* W1 = (const float*)d_in[13];
  const float* b1 = (const float*)d_in[14];
  const float* W2 = (const float*)d_in[15];
  const float* b2 = (const float*)d_in[16];
  float* out = (float*)d_out;

  char* ws = (char*)d_ws;
  const size_t MB = 1024ull * 1024ull;
  us* WqkvT = (us*)(ws + 0);          // [3072][1024] bf16
  us* WoT   = (us*)(ws + 6 * MB);     // [1024][1024]
  us* W1T   = (us*)(ws + 8 * MB);     // [4096][1024]
  us* W2T   = (us*)(ws + 16 * MB);    // [1024][4096]
  us* hbuf  = (us*)(ws + 24 * MB);    // [8192][1024] bf16 (LN1 out)
  us* qkvb  = (us*)(ws + 40 * MB);    // [8192][3072] bf16
  us* ybuf  = (us*)(ws + 88 * MB);    // [8192][1024] bf16
  float* x1 = (float*)(ws + 104 * MB);// [8192][1024] f32
  us* h2    = (us*)(ws + 136 * MB);   // [8192][1024] bf16
  us* ff1   = (us*)(ws + 24 * MB);    // [8192][4096] bf16 (reuses h/qkv region)
  float* bqkv = (float*)(ws + 152 * MB); // [3072] f32

  transpose_cast<<<dim3(32, 32), 256, 0, stream>>>(Wq, WqkvT, 1024, 1024, QSCALE);
  transpose_cast<<<dim3(32, 32), 256, 0, stream>>>(Wk, WqkvT + 1024 * 1024, 1024, 1024, 1.f);
  transpose_cast<<<dim3(32, 32), 256, 0, stream>>>(Wv, WqkvT + 2 * 1024 * 1024, 1024, 1024, 1.f);
  transpose_cast<<<dim3(32, 32), 256, 0, stream>>>(Wo, WoT, 1024, 1024, 1.f);
  transpose_cast<<<dim3(128, 32), 256, 0, stream>>>(W1, W1T, 1024, 4096, 1.f);
  transpose_cast<<<dim3(32, 128), 256, 0, stream>>>(W2, W2T, 4096, 1024, 1.f);
  pack_bias<<<12, 256, 0, stream>>>(bq, bk, bv, bqkv);

  ln_kernel<<<NTOK, 256, 0, stream>>>(x, g1, be1, hbuf);
  // QKV: M=8192 N=3072 K=1024 -> 32x12 = 384 blocks, BM=256 BN=256
  gemm256<<<dim3(384), 512, 0, stream>>>(hbuf, WqkvT, bqkv, qkvb, 3072, 1024, 0, 12);
  attn<<<1024, 256, 0, stream>>>(qkvb, ybuf);
  // proj: M=8192 N=1024 K=1024 -> 64x4 = 256 blocks, BM=128 BN=256, resid=x -> x1
  gemm128<<<dim3(256), 512, 0, stream>>>(ybuf, WoT, bo, x, x1, 1024, 1024, 4);
  ln_kernel<<<NTOK, 256, 0, stream>>>(x1, g2, be2, h2);
  // FF1: M=8192 N=4096 K=1024 -> 32x16 = 512 blocks, gelu
  gemm256<<<dim3(512), 512, 0, stream>>>(h2, W1T, b1, ff1, 4096, 1024, 1, 16);
  // FF2: M=8192 N=1024 K=4096 -> 64x4 = 256 blocks, resid=x1 -> out
  gemm128<<<dim3(256), 512, 0, stream>>>(ff1, W2T, b2, x1, out, 1024, 4096, 4);
}

// Round 6
// 486.702 us; speedup vs baseline: 1.2905x; 1.0678x over previous
//
#include <hip/hip_runtime.h>
#include <hip/hip_bf16.h>
#include <stdint.h>
#include <math.h>

#define SEQ 2048
#define NTOK 8192        // B*S
#define EMB 1024
#define NH 16
#define HD 64
#define FFD 4096
#define QSCALE 0.1803368801111137f   // 0.125 * log2(e), folded into Wq/bq

using us = unsigned short;
using b8 = __attribute__((ext_vector_type(8))) __bf16;
using f4 = __attribute__((ext_vector_type(4))) float;

__device__ __forceinline__ us f2b(float f) {
  union { float f; uint32_t u; } v; v.f = f;
  uint32_t u = v.u;
  return (us)((u + 0x7fffu + ((u >> 16) & 1u)) >> 16);  // RNE
}

// pack two fp32 -> bf16x2 (round-half-up; P >= 0, bias negligible)
__device__ __forceinline__ uint32_t pkbf(float a, float b) {
  union { float f; uint32_t u; } x, y; x.f = a; y.f = b;
  return ((x.u + 0x8000u) >> 16) | ((y.u + 0x8000u) & 0xFFFF0000u);
}

__device__ __forceinline__ void async16(void* lds, const void* g) {
  __builtin_amdgcn_global_load_lds(
      (__attribute__((address_space(1))) void*)(uintptr_t)g,
      (__attribute__((address_space(3))) void*)(uintptr_t)lds, 16, 0, 0);
}

#define FENCED_BARRIER() do { asm volatile("" ::: "memory"); \
  __builtin_amdgcn_s_barrier(); asm volatile("" ::: "memory"); } while (0)

// tanh-form GELU: 0.5x(1+tanh(k0(x+k1 x^3))) = x*sigmoid(2 k0 (x+k1 x^3))
// |err vs exact erf-gelu| < ~1e-3, below ff1's bf16 quantization.
__device__ __forceinline__ float gelu_f(float x) {
  const float z = -2.30211416f * x * (1.f + 0.044715f * x * x);
  return x / (1.f + __builtin_amdgcn_exp2f(z));
}

// ======= fused prep: 6 weight transposes + bias pack + LN1, ONE dispatch =======
// All parts are mutually independent; fusing 8 kernels into 1 removes ~8 graph-node
// launch overheads and lets small transposes overlap the LN1 memory stream.
// Block map: [0,4096) 4x 1024^2 transposes (Wq scaled by QSCALE) | [4096,8192) W1
// | [8192,12288) W2 | [12288,12300) pack_bias | [12300,20492) LN1 rows.
__global__ __launch_bounds__(256)
void prep(const float* __restrict__ Wq, const float* __restrict__ Wk,
          const float* __restrict__ Wv, const float* __restrict__ Wo,
          const float* __restrict__ W1, const float* __restrict__ W2,
          const float* __restrict__ bq, const float* __restrict__ bk,
          const float* __restrict__ bv,
          const float* __restrict__ x, const float* __restrict__ g1,
          const float* __restrict__ be1,
          us* __restrict__ WqkvT, us* __restrict__ WoT, us* __restrict__ W1T,
          us* __restrict__ W2T, float* __restrict__ bqkv, us* __restrict__ hbuf) {
  __shared__ float tile[32][33];
  __shared__ float red[8];
  const int bid = blockIdx.x;
  const int t = threadIdx.x;

  if (bid < 12288) {                       // ---- transpose+cast region ----
    int R, C, csh, t0; const float* in; us* out; float sc = 1.f;
    if (bid < 4096) {
      R = 1024; C = 1024; csh = 5; t0 = bid & 1023;
      const int m = bid >> 10;
      in  = (m == 0) ? Wq : (m == 1) ? Wk : (m == 2) ? Wv : Wo;
      out = (m == 0) ? WqkvT : (m == 1) ? (WqkvT + (1 << 20))
          : (m == 2) ? (WqkvT + (2 << 20)) : WoT;
      if (m == 0) sc = QSCALE;
    } else if (bid < 8192) {
      R = 1024; C = 4096; csh = 7; t0 = bid - 4096; in = W1; out = W1T;
    } else {
      R = 4096; C = 1024; csh = 5; t0 = bid - 8192; in = W2; out = W2T;
    }
    const int bc = (t0 & ((1 << csh) - 1)) << 5;
    const int br = (t0 >> csh) << 5;
    const int tx = t & 31, ty = t >> 5;
#pragma unroll
    for (int i = 0; i < 32; i += 8)
      tile[ty + i][tx] = in[(size_t)(br + ty + i) * C + bc + tx];
    __syncthreads();
#pragma unroll
    for (int i = 0; i < 32; i += 8)
      out[(size_t)(bc + ty + i) * R + br + tx] = f2b(tile[tx][ty + i] * sc);

  } else if (bid < 12300) {                // ---- pack_bias region ----
    const int i = (bid - 12288) * 256 + t;
    bqkv[i] = (i < 1024) ? bq[i] * QSCALE : (i < 2048 ? bk[i - 1024] : bv[i - 2048]);

  } else {                                 // ---- LN1 region ----
    const int row = bid - 12300;
    const float4 v = ((const float4*)(x + (size_t)row * EMB))[t];
    float s = v.x + v.y + v.z + v.w;
    float s2 = v.x * v.x + v.y * v.y + v.z * v.z + v.w * v.w;
#pragma unroll
    for (int o = 32; o; o >>= 1) { s += __shfl_down(s, o, 64); s2 += __shfl_down(s2, o, 64); }
    if ((t & 63) == 0) { red[(t >> 6) * 2] = s; red[(t >> 6) * 2 + 1] = s2; }
    __syncthreads();
    const float ts = red[0] + red[2] + red[4] + red[6];
    const float ts2 = red[1] + red[3] + red[5] + red[7];
    const float mu = ts * (1.f / 1024.f);
    const float rs = rsqrtf(ts2 * (1.f / 1024.f) - mu * mu + 1e-5f);
    const float4 gv = ((const float4*)g1)[t];
    const float4 bv4 = ((const float4*)be1)[t];
    ushort4 o4;
    o4.x = f2b((v.x - mu) * rs * gv.x + bv4.x);
    o4.y = f2b((v.y - mu) * rs * gv.y + bv4.y);
    o4.z = f2b((v.z - mu) * rs * gv.z + bv4.z);
    o4.w = f2b((v.w - mu) * rs * gv.w + bv4.w);
    ((ushort4*)(hbuf + (size_t)row * EMB))[t] = o4;
  }
}

// ---------------- LayerNorm: fp32 in -> bf16 out, one block per token ----------------
__global__ __launch_bounds__(256)
void ln_kernel(const float* __restrict__ x, const float* __restrict__ g,
               const float* __restrict__ be, us* __restrict__ out) {
  __shared__ float red[8];
  const int row = blockIdx.x, t = threadIdx.x;
  const float4 v = ((const float4*)(x + (size_t)row * EMB))[t];
  float s = v.x + v.y + v.z + v.w;
  float s2 = v.x * v.x + v.y * v.y + v.z * v.z + v.w * v.w;
#pragma unroll
  for (int o = 32; o; o >>= 1) { s += __shfl_down(s, o, 64); s2 += __shfl_down(s2, o, 64); }
  if ((t & 63) == 0) { red[(t >> 6) * 2] = s; red[(t >> 6) * 2 + 1] = s2; }
  __syncthreads();
  const float ts = red[0] + red[2] + red[4] + red[6];
  const float ts2 = red[1] + red[3] + red[5] + red[7];
  const float mu = ts * (1.f / 1024.f);
  const float rs = rsqrtf(ts2 * (1.f / 1024.f) - mu * mu + 1e-5f);
  const float4 gv = ((const float4*)g)[t];
  const float4 bv = ((const float4*)be)[t];
  ushort4 o4;
  o4.x = f2b((v.x - mu) * rs * gv.x + bv.x);
  o4.y = f2b((v.y - mu) * rs * gv.y + bv.y);
  o4.z = f2b((v.z - mu) * rs * gv.z + bv.z);
  o4.w = f2b((v.w - mu) * rs * gv.w + bv.w);
  ((ushort4*)(out + (size_t)row * EMB))[t] = o4;
}

// ================= 8-phase GEMM, BM=256 x BN=256, BK=64, 8 waves (2M x 4N) =================
// (unchanged from round 3 -- vmcnt(6) counted pipeline, T2 XOR swizzle, T5 setprio)
__global__ __launch_bounds__(512, 2)
void gemm256(const us* __restrict__ A, const us* __restrict__ Bt,
             const float* __restrict__ bias, us* __restrict__ outB,
             int N, int K, int gelu, int gy) {
  __shared__ us As[2][256 * 64];   // 64 KB
  __shared__ us Bs[2][256 * 64];   // 64 KB

  int bid = blockIdx.x;
  const int cpx = (int)gridDim.x >> 3;         // grid % 8 == 0 always here
  bid = (bid & 7) * cpx + (bid >> 3);          // bijective XCD swizzle
  const int bx = bid / gy, by = bid - bx * gy;
  const int row0 = bx * 256, col0 = by * 256;

  const int tid = threadIdx.x, w = tid >> 6, lane = tid & 63;
  const int wm = w >> 2, wn = w & 3;
  const int quad = lane >> 4, l15 = lane & 15;
  const int xr = l15 & 7;

  const int u0 = w * 2, u1 = u0 + 1;
  const int ar0 = ((u0 & 7) << 3) + ((u0 >> 3) << 7);   // A: {0..56} + {0,128}
  const int ar1 = ((u1 & 7) << 3) + ((u1 >> 3) << 7);
  const int br0 = ((u0 & 3) << 3) + ((u0 >> 2) << 6);   // B: {0..24} + {0,64,128,192}
  const int br1 = ((u1 & 3) << 3) + ((u1 >> 2) << 6);
  const int lrow = lane >> 3;
  const int loct = ((lane & 7) ^ lrow) << 3;            // inverse-swizzled source octet
  const us* Ag0 = A + (size_t)(row0 + ar0 + lrow) * K + loct;
  const us* Ag1 = A + (size_t)(row0 + ar1 + lrow) * K + loct;
  const us* Bg0 = Bt + (size_t)(col0 + br0 + lrow) * K + loct;
  const us* Bg1 = Bt + (size_t)(col0 + br1 + lrow) * K + loct;
  const int NT = K >> 6;

  const f4 zf = {0.f, 0.f, 0.f, 0.f};
  f4 acc[8][4];
#pragma unroll
  for (int i = 0; i < 8; i++)
#pragma unroll
    for (int j = 0; j < 4; j++) acc[i][j] = zf;

  auto stgA = [&](int buf, int t, int mh) {
    const size_t go = (size_t)(mh << 6) * K + ((size_t)t << 6);
    async16(&As[buf][(ar0 + (mh << 6)) << 6], Ag0 + go);
    async16(&As[buf][(ar1 + (mh << 6)) << 6], Ag1 + go);
  };
  auto stgB = [&](int buf, int t, int nh) {
    const size_t go = (size_t)(nh << 5) * K + ((size_t)t << 6);
    async16(&Bs[buf][(br0 + (nh << 5)) << 6], Bg0 + go);
    async16(&Bs[buf][(br1 + (nh << 5)) << 6], Bg1 + go);
  };

  stgA(0, 0, 0); stgB(0, 0, 0); stgB(0, 0, 1); stgA(0, 0, 1);
  stgA(1, 1, 0); stgB(1, 1, 0); stgB(1, 1, 1);
  asm volatile("s_waitcnt vmcnt(6)" ::: "memory");
  FENCED_BARRIER();

  for (int t = 0; t < NT; t++) {
    const int cur = t & 1, nxt = cur ^ 1;
    const us* __restrict__ as = As[cur];
    const us* __restrict__ bs = Bs[cur];
    b8 af[2][4], bf0[2][2], bf1[2][2];

    // ---- phase 1 (mh0, nh0): 12 ds_reads, stage U4(t+1)
#pragma unroll
    for (int s = 0; s < 2; s++) {
      const int po = (((s << 2) + quad) ^ xr) << 3;
#pragma unroll
      for (int mi = 0; mi < 4; mi++)
        af[s][mi] = *(const b8*)&as[(wm * 128 + mi * 16 + l15) * 64 + po];
#pragma unroll
      for (int nf = 0; nf < 2; nf++)
        bf0[s][nf] = *(const b8*)&bs[(wn * 64 + nf * 16 + l15) * 64 + po];
    }
    if (t + 1 < NT) stgA(nxt, t + 1, 1);
    FENCED_BARRIER();
    asm volatile("s_waitcnt lgkmcnt(0)" ::: "memory");
    __builtin_amdgcn_s_setprio(1);
#pragma unroll
    for (int s = 0; s < 2; s++)
#pragma unroll
      for (int mi = 0; mi < 4; mi++)
#pragma unroll
        for (int nf = 0; nf < 2; nf++)
          acc[mi][nf] = __builtin_amdgcn_mfma_f32_16x16x32_bf16(af[s][mi], bf0[s][nf], acc[mi][nf], 0, 0, 0);
    __builtin_amdgcn_s_setprio(0);
    FENCED_BARRIER();

    // ---- phase 2 (mh0, nh1): 4 ds_reads, stage U1(t+2)
#pragma unroll
    for (int s = 0; s < 2; s++) {
      const int po = (((s << 2) + quad) ^ xr) << 3;
#pragma unroll
      for (int nf = 0; nf < 2; nf++)
        bf1[s][nf] = *(const b8*)&bs[(wn * 64 + 32 + nf * 16 + l15) * 64 + po];
    }
    if (t + 2 < NT) stgA(cur, t + 2, 0);
    FENCED_BARRIER();
    asm volatile("s_waitcnt lgkmcnt(0)" ::: "memory");
    __builtin_amdgcn_s_setprio(1);
#pragma unroll
    for (int s = 0; s < 2; s++)
#pragma unroll
      for (int mi = 0; mi < 4; mi++)
#pragma unroll
        for (int nf = 0; nf < 2; nf++)
          acc[mi][2 + nf] = __builtin_amdgcn_mfma_f32_16x16x32_bf16(af[s][mi], bf1[s][nf], acc[mi][2 + nf], 0, 0, 0);
    __builtin_amdgcn_s_setprio(0);
    FENCED_BARRIER();

    // ---- phase 3 (mh1, nh0): 8 ds_reads, stage U2(t+2)
#pragma unroll
    for (int s = 0; s < 2; s++) {
      const int po = (((s << 2) + quad) ^ xr) << 3;
#pragma unroll
      for (int mi = 0; mi < 4; mi++)
        af[s][mi] = *(const b8*)&as[(wm * 128 + 64 + mi * 16 + l15) * 64 + po];
    }
    if (t + 2 < NT) stgB(cur, t + 2, 0);
    FENCED_BARRIER();
    asm volatile("s_waitcnt lgkmcnt(0)" ::: "memory");
    __builtin_amdgcn_s_setprio(1);
#pragma unroll
    for (int s = 0; s < 2; s++)
#pragma unroll
      for (int mi = 0; mi < 4; mi++)
#pragma unroll
        for (int nf = 0; nf < 2; nf++)
          acc[4 + mi][nf] = __builtin_amdgcn_mfma_f32_16x16x32_bf16(af[s][mi], bf0[s][nf], acc[4 + mi][nf], 0, 0, 0);
    __builtin_amdgcn_s_setprio(0);
    FENCED_BARRIER();

    // ---- phase 4 (mh1, nh1): 0 ds_reads, stage U3(t+2), once-per-tile vmcnt
    if (t + 2 < NT) {
      stgB(cur, t + 2, 1);
      asm volatile("s_waitcnt vmcnt(6)" ::: "memory");   // retires all of tile t+1
    } else {
      asm volatile("s_waitcnt vmcnt(0)" ::: "memory");
    }
    FENCED_BARRIER();
    __builtin_amdgcn_s_setprio(1);
#pragma unroll
    for (int s = 0; s < 2; s++)
#pragma unroll
      for (int mi = 0; mi < 4; mi++)
#pragma unroll
        for (int nf = 0; nf < 2; nf++)
          acc[4 + mi][2 + nf] = __builtin_amdgcn_mfma_f32_16x16x32_bf16(af[s][mi], bf1[s][nf], acc[4 + mi][2 + nf], 0, 0, 0);
    __builtin_amdgcn_s_setprio(0);
    FENCED_BARRIER();
  }

#pragma unroll
  for (int mi8 = 0; mi8 < 8; mi8++)
#pragma unroll
    for (int nf = 0; nf < 4; nf++) {
      const int gcol = col0 + wn * 64 + nf * 16 + l15;
      const float bc = bias[gcol];
#pragma unroll
      for (int r = 0; r < 4; r++) {
        const int grow = row0 + wm * 128 + mi8 * 16 + quad * 4 + r;
        float v = acc[mi8][nf][r] + bc;
        if (gelu) v = gelu_f(v);
        outB[(size_t)grow * N + gcol] = f2b(v);
      }
    }
}

// ================= 8-phase GEMM, BM=128 x BN=256 (f32 out + resid) ==================
// (unchanged from round 3)
__global__ __launch_bounds__(512, 2)
void gemm128(const us* __restrict__ A, const us* __restrict__ Bt,
             const float* __restrict__ bias, const float* __restrict__ resid,
             float* __restrict__ outF, int N, int K, int gy) {
  __shared__ us As[2][128 * 64];   // 32 KB
  __shared__ us Bs[2][256 * 64];   // 64 KB

  int bid = blockIdx.x;
  const int cpx = (int)gridDim.x >> 3;
  bid = (bid & 7) * cpx + (bid >> 3);
  const int bx = bid / gy, by = bid - bx * gy;
  const int row0 = bx * 128, col0 = by * 256;

  const int tid = threadIdx.x, w = tid >> 6, lane = tid & 63;
  const int wm = w >> 2, wn = w & 3;
  const int quad = lane >> 4, l15 = lane & 15;
  const int xr = l15 & 7;

  const int u0 = w * 2, u1 = u0 + 1;
  const int aR0 = u0 << 3, aR1 = u1 << 3;               // A rows 0..127
  const int bR0 = ((u0 & 3) << 3) + ((u0 >> 2) << 6);
  const int bR1 = ((u1 & 3) << 3) + ((u1 >> 2) << 6);
  const int lrow = lane >> 3;
  const int loct = ((lane & 7) ^ lrow) << 3;
  const us* Ag0 = A + (size_t)(row0 + aR0 + lrow) * K + loct;
  const us* Ag1 = A + (size_t)(row0 + aR1 + lrow) * K + loct;
  const us* Bg0 = Bt + (size_t)(col0 + bR0 + lrow) * K + loct;
  const us* Bg1 = Bt + (size_t)(col0 + bR1 + lrow) * K + loct;
  const int NT = K >> 6;

  const f4 zf = {0.f, 0.f, 0.f, 0.f};
  f4 acc[4][4];
#pragma unroll
  for (int i = 0; i < 4; i++)
#pragma unroll
    for (int j = 0; j < 4; j++) acc[i][j] = zf;

  auto stgA = [&](int buf, int t) {
    const size_t go = (size_t)t << 6;
    async16(&As[buf][aR0 << 6], Ag0 + go);
    async16(&As[buf][aR1 << 6], Ag1 + go);
  };
  auto stgB = [&](int buf, int t, int nh) {
    const size_t go = (size_t)(nh << 5) * K + ((size_t)t << 6);
    async16(&Bs[buf][(bR0 + (nh << 5)) << 6], Bg0 + go);
    async16(&Bs[buf][(bR1 + (nh << 5)) << 6], Bg1 + go);
  };

  stgA(0, 0); stgB(0, 0, 0); stgB(0, 0, 1);
  stgA(1, 1); stgB(1, 1, 0);
  asm volatile("s_waitcnt vmcnt(6)" ::: "memory");
  FENCED_BARRIER();

  for (int t = 0; t < NT; t++) {
    const int cur = t & 1, nxt = cur ^ 1;
    const us* __restrict__ as = As[cur];
    const us* __restrict__ bs = Bs[cur];
    b8 af[2][4], bf0[2][2], bf1[2][2];

    // ---- phase 1: 12 ds_reads, stage UB1(t+1), retire UB1(t)
#pragma unroll
    for (int s = 0; s < 2; s++) {
      const int po = (((s << 2) + quad) ^ xr) << 3;
#pragma unroll
      for (int mi = 0; mi < 4; mi++)
        af[s][mi] = *(const b8*)&as[(wm * 64 + mi * 16 + l15) * 64 + po];
#pragma unroll
      for (int nf = 0; nf < 2; nf++)
        bf0[s][nf] = *(const b8*)&bs[(wn * 64 + nf * 16 + l15) * 64 + po];
    }
    if (t + 1 < NT) {
      stgB(nxt, t + 1, 1);
      asm volatile("s_waitcnt vmcnt(6)" ::: "memory");
    } else {
      asm volatile("s_waitcnt vmcnt(0)" ::: "memory");
    }
    FENCED_BARRIER();
    asm volatile("s_waitcnt lgkmcnt(0)" ::: "memory");
    __builtin_amdgcn_s_setprio(1);
#pragma unroll
    for (int s = 0; s < 2; s++)
#pragma unroll
      for (int mi = 0; mi < 4; mi++)
#pragma unroll
        for (int nf = 0; nf < 2; nf++)
          acc[mi][nf] = __builtin_amdgcn_mfma_f32_16x16x32_bf16(af[s][mi], bf0[s][nf], acc[mi][nf], 0, 0, 0);
    __builtin_amdgcn_s_setprio(0);
    FENCED_BARRIER();

    // ---- phase 2: 4 ds_reads, stage UA(t+2)+UB0(t+2), retire UA,UB0(t+1)
#pragma unroll
    for (int s = 0; s < 2; s++) {
      const int po = (((s << 2) + quad) ^ xr) << 3;
#pragma unroll
      for (int nf = 0; nf < 2; nf++)
        bf1[s][nf] = *(const b8*)&bs[(wn * 64 + 32 + nf * 16 + l15) * 64 + po];
    }
    if (t + 2 < NT) {
      stgA(cur, t + 2); stgB(cur, t + 2, 0);
      asm volatile("s_waitcnt vmcnt(6)" ::: "memory");
    } else {
      asm volatile("s_waitcnt vmcnt(2)" ::: "memory");
    }
    FENCED_BARRIER();
    asm volatile("s_waitcnt lgkmcnt(0)" ::: "memory");
    __builtin_amdgcn_s_setprio(1);
#pragma unroll
    for (int s = 0; s < 2; s++)
#pragma unroll
      for (int mi = 0; mi < 4; mi++)
#pragma unroll
        for (int nf = 0; nf < 2; nf++)
          acc[mi][2 + nf] = __builtin_amdgcn_mfma_f32_16x16x32_bf16(af[s][mi], bf1[s][nf], acc[mi][2 + nf], 0, 0, 0);
    __builtin_amdgcn_s_setprio(0);
    FENCED_BARRIER();
  }

#pragma unroll
  for (int mi = 0; mi < 4; mi++)
#pragma unroll
    for (int nf = 0; nf < 4; nf++) {
      const int gcol = col0 + wn * 64 + nf * 16 + l15;
      const float bc = bias[gcol];
#pragma unroll
      for (int r = 0; r < 4; r++) {
        const int grow = row0 + wm * 64 + mi * 16 + quad * 4 + r;
        outF[(size_t)grow * N + gcol] = acc[mi][nf][r] + bc + resid[(size_t)grow * N + gcol];
      }
    }
}

// ---------------- causal flash attention, operand-swapped, reg-blocked ----------------
// qkv: [NTOK][3072] bf16 (q|k|v), Q pre-scaled by QSCALE. y: [NTOK][1024] bf16.
// Round-6: V^T DOUBLE-buffered in LDS (50 KB total, still 3 blocks/CU). The prefetched
// V registers now die mid-iteration (written to Vt[nxt] after softmax) instead of
// living across the loop barrier -- removes the r5 scratch spill (WRITE_SIZE 73 MB).
// defer-max THR=8; sm_scale folded into Q at prep; setprio on MFMA clusters.
__global__ __launch_bounds__(256, 3)
void attn(const us* __restrict__ qkv, us* __restrict__ y) {
  // magic-square qt mapping: each CU-coset of blocks gets equal total work
  static const signed char QTM[16] = {15,14,13,12, 10,11,8,9, 5,4,7,6, 0,1,2,3};
  const int bx = blockIdx.x;
  const int bh = bx & 63;
  const int qt = QTM[(bx >> 6) & 15];
  const int bb = bh >> 4, h = bh & 15;
  const int tid = threadIdx.x;
  const int wave = tid >> 6, lane = tid & 63;
  const int quad = lane >> 4, l15 = lane & 15;

  __shared__ us Ks[128 * 64];      // 16 KB; phys us off = row*64 + ((col8 ^ (row&7))<<3)
  __shared__ us Vt[2][64 * 132];   // 33 KB; V^T[d][key], us off = d*132 + key

  const size_t base = (size_t)bb * SEQ * 3072;
  const int q0 = qt * 128;

  // Q B-fragments for two 16-q groups (rows wave*32 + qg*16 + l15)
  b8 bqf[2][2];
#pragma unroll
  for (int qg = 0; qg < 2; qg++) {
    const us* qp = qkv + base + (size_t)(q0 + wave * 32 + qg * 16 + l15) * 3072 + h * 64 + quad * 8;
    bqf[qg][0] = *(const b8*)qp;
    bqf[qg][1] = *(const b8*)(qp + 32);
  }

  const f4 zf = {0.f, 0.f, 0.f, 0.f};
  f4 o[2][4];                       // [qg][dg]: O[q=quad*4+r][d=dg*16+l15]
  float mrow[2], lrow[2];
#pragma unroll
  for (int qg = 0; qg < 2; qg++) {
    mrow[qg] = -3.0e38f; lrow[qg] = 0.f;
#pragma unroll
    for (int dg = 0; dg < 4; dg++) o[qg][dg] = zf;
  }

  // K staging: wave stages rows wave*32..+31 in 4 DMA ops of 8 rows.
  const int klr = lane >> 3, klc = lane & 7;
  const us* kgbase = qkv + base + (size_t)(wave * 32 + klr) * 3072 + 1024 + h * 64 + ((klc ^ klr) << 3);
  // V staging: thread handles key pair (2*lane, 2*lane+1), d-octets wave*8 and 32+wave*8.
  const us* vgbase = qkv + base + (size_t)(2 * lane) * 3072 + 2048 + h * 64 + wave * 8;

  // prologue: V(tile 0) -> regs -> Vt[0]  (regs die here)
  {
    union { float4 f; us u[8]; } v0, v1, v2, v3;
    v0.f = *(const float4*)(vgbase);
    v1.f = *(const float4*)(vgbase + 3072);
    v2.f = *(const float4*)(vgbase + 32);
    v3.f = *(const float4*)(vgbase + 3072 + 32);
#pragma unroll
    for (int j = 0; j < 8; j++) {
      *(uint32_t*)&Vt[0][(wave * 8 + j) * 132 + 2 * lane] =
          (uint32_t)v0.u[j] | ((uint32_t)v1.u[j] << 16);
      *(uint32_t*)&Vt[0][(32 + wave * 8 + j) * 132 + 2 * lane] =
          (uint32_t)v2.u[j] | ((uint32_t)v3.u[j] << 16);
    }
  }

  for (int kt = 0; kt <= qt; kt++) {
    const int cur = kt & 1, nxt = cur ^ 1;
    const size_t koff = (size_t)kt * 128 * 3072;
    // --- stage K (async DMA, XOR-swizzled source) ---
#pragma unroll
    for (int op = 0; op < 4; op++)
      async16(&Ks[(wave * 32 + op * 8) * 64], kgbase + koff + (size_t)op * 8 * 3072);
    // --- issue V(kt+1) prefetch; counted vmcnt leaves it in flight across barrier ---
    float4 vb0, vb1, vb2, vb3;
    if (kt < qt) {
      const us* vg = vgbase + koff + (size_t)128 * 3072;
      vb0 = *(const float4*)(vg);
      vb1 = *(const float4*)(vg + 3072);
      vb2 = *(const float4*)(vg + 32);
      vb3 = *(const float4*)(vg + 3072 + 32);
      asm volatile("s_waitcnt vmcnt(4)" ::: "memory");   // K DMA landed; V loads in flight
    } else {
      asm volatile("s_waitcnt vmcnt(0)" ::: "memory");   // K DMA landed
    }
    asm volatile("s_waitcnt lgkmcnt(0)" ::: "memory");   // Vt writes (prev iter) visible
    FENCED_BARRIER();

    // --- S^T = K·Q^T : sacc[qg][c] holds S^T[key=c*16+quad*4+r][q=l15] ---
    f4 sacc[2][8];
    __builtin_amdgcn_s_setprio(1);
#pragma unroll
    for (int c = 0; c < 8; c++) {
      const int krow = (c * 16 + l15) * 64;
      const int sw = l15 & 7;
      const b8 ak0 = *(const b8*)&Ks[krow + ((quad ^ sw) << 3)];
      const b8 ak1 = *(const b8*)&Ks[krow + (((quad ^ 4) ^ sw) << 3)];
#pragma unroll
      for (int qg = 0; qg < 2; qg++) {
        f4 s = __builtin_amdgcn_mfma_f32_16x16x32_bf16(ak0, bqf[qg][0], zf, 0, 0, 0);
        sacc[qg][c] = __builtin_amdgcn_mfma_f32_16x16x32_bf16(ak1, bqf[qg][1], s, 0, 0, 0);
      }
    }
    __builtin_amdgcn_s_setprio(0);

    // --- softmax per q-group (scores already in log2 units; defer-max THR=8) ---
    uint32_t pf[2][16];
#pragma unroll
    for (int qg = 0; qg < 2; qg++) {
      const int q_in = wave * 32 + qg * 16 + l15;
      if (kt == qt) {
#pragma unroll
        for (int c = 0; c < 8; c++)
#pragma unroll
          for (int r = 0; r < 4; r++)
            if ((c * 16 + quad * 4 + r) > q_in) sacc[qg][c][r] = -3.0e38f;
      }
      float mx = sacc[qg][0][0];
#pragma unroll
      for (int c = 0; c < 8; c++)
#pragma unroll
        for (int r = 0; r < 4; r++) mx = fmaxf(mx, sacc[qg][c][r]);
      mx = fmaxf(mx, __shfl_xor(mx, 16, 64));
      mx = fmaxf(mx, __shfl_xor(mx, 32, 64));
      if (!__all(mx - mrow[qg] <= 8.f)) {   // wave-uniform; P bounded by 2^8 when deferred
        const float mnew = fmaxf(mrow[qg], mx);
        const float al = __builtin_amdgcn_exp2f(mrow[qg] - mnew);
        mrow[qg] = mnew;
        lrow[qg] *= al;
#pragma unroll
        for (int r = 0; r < 4; r++) {
          const float ar = __shfl(al, quad * 4 + r, 64);
#pragma unroll
          for (int dg = 0; dg < 4; dg++) o[qg][dg][r] *= ar;
        }
      }
      const float mb = mrow[qg];
      float rs = 0.f;
#pragma unroll
      for (int c = 0; c < 8; c++) {
        const float p0 = __builtin_amdgcn_exp2f(sacc[qg][c][0] - mb);
        const float p1 = __builtin_amdgcn_exp2f(sacc[qg][c][1] - mb);
        const float p2 = __builtin_amdgcn_exp2f(sacc[qg][c][2] - mb);
        const float p3 = __builtin_amdgcn_exp2f(sacc[qg][c][3] - mb);
        rs += (p0 + p1) + (p2 + p3);
        pf[qg][c * 2] = pkbf(p0, p1);
        pf[qg][c * 2 + 1] = pkbf(p2, p3);
      }
      rs += __shfl_xor(rs, 16, 64);
      rs += __shfl_xor(rs, 32, 64);
      lrow[qg] += rs;
    }

    // --- write V(kt+1) into Vt[nxt] NOW (prefetch regs die here, pre-PV) ---
    if (kt < qt) {
      asm volatile("s_waitcnt vmcnt(0)" ::: "memory");   // V loads arrived (hidden under QK+SM)
      union { float4 f; us u[8]; } v0, v1, v2, v3;
      v0.f = vb0; v1.f = vb1; v2.f = vb2; v3.f = vb3;
#pragma unroll
      for (int j = 0; j < 8; j++) {
        *(uint32_t*)&Vt[nxt][(wave * 8 + j) * 132 + 2 * lane] =
            (uint32_t)v0.u[j] | ((uint32_t)v1.u[j] << 16);
        *(uint32_t*)&Vt[nxt][(32 + wave * 8 + j) * 132 + 2 * lane] =
            (uint32_t)v2.u[j] | ((uint32_t)v3.u[j] << 16);
      }
    }

    // --- O += P·V : V b64 reads shared across q-groups; zero-padded halves ---
    __builtin_amdgcn_s_setprio(1);
#pragma unroll
    for (int c = 0; c < 8; c++) {
      union { uint32_t w[4]; b8 v; } af0, af1;
      af0.w[0] = pf[0][c * 2]; af0.w[1] = pf[0][c * 2 + 1]; af0.w[2] = 0u; af0.w[3] = 0u;
      af1.w[0] = pf[1][c * 2]; af1.w[1] = pf[1][c * 2 + 1]; af1.w[2] = 0u; af1.w[3] = 0u;
#pragma unroll
      for (int dg = 0; dg < 4; dg++) {
        const uint2 vd = *(const uint2*)&Vt[cur][(dg * 16 + l15) * 132 + c * 16 + quad * 4];
        union { uint32_t w[4]; b8 v; } vb;
        vb.w[0] = vd.x; vb.w[1] = vd.y; vb.w[2] = 0u; vb.w[3] = 0u;
        o[0][dg] = __builtin_amdgcn_mfma_f32_16x16x32_bf16(af0.v, vb.v, o[0][dg], 0, 0, 0);
        o[1][dg] = __builtin_amdgcn_mfma_f32_16x16x32_bf16(af1.v, vb.v, o[1][dg], 0, 0, 0);
      }
    }
    __builtin_amdgcn_s_setprio(0);
    asm volatile("s_waitcnt lgkmcnt(0)" ::: "memory");   // PV reads + Vt[nxt] writes retired
    FENCED_BARRIER();   // Ks/Vt[cur] safe to overwrite next iter
  }

#pragma unroll
  for (int qg = 0; qg < 2; qg++) {
    float lr[4];
#pragma unroll
    for (int r = 0; r < 4; r++) lr[r] = __shfl(lrow[qg], quad * 4 + r, 64);
#pragma unroll
    for (int dg = 0; dg < 4; dg++)
#pragma unroll
      for (int r = 0; r < 4; r++) {
        const int gq = q0 + wave * 32 + qg * 16 + quad * 4 + r;
        y[(size_t)(bb * SEQ + gq) * EMB + h * 64 + dg * 16 + l15] = f2b(o[qg][dg][r] / lr[r]);
      }
  }
}

extern "C" void kernel_launch(void* const* d_in, const int* in_sizes, int n_in,
                              void* d_out, int out_size, void* d_ws, size_t ws_size,
                              hipStream_t stream) {
  const float* x = (const float*)d_in[0];
  const float* Wq = (const float*)d_in[1];
  const float* bq = (const float*)d_in[2];
  const float* Wk = (const float*)d_in[3];
  const float* bk = (const float*)d_in[4];
  const float* Wv = (const float*)d_in[5];
  const float* bv = (const float*)d_in[6];
  const float* Wo = (const float*)d_in[7];
  const float* bo = (const float*)d_in[8];
  const float* g1 = (const float*)d_in[9];
  const float* be1 = (const float*)d_in[10];
  const float* g2 = (const float*)d_in[11];
  const float* be2 = (const float*)d_in[12];
  const float* W1 = (const float*)d_in[13];
  const float* b1 = (const float*)d_in[14];
  const float* W2 = (const float*)d_in[15];
  const float* b2 = (const float*)d_in[16];
  float* out = (float*)d_out;

  char* ws = (char*)d_ws;
  const size_t MB = 1024ull * 1024ull;
  us* WqkvT = (us*)(ws + 0);          // [3072][1024] bf16
  us* WoT   = (us*)(ws + 6 * MB);     // [1024][1024]
  us* W1T   = (us*)(ws + 8 * MB);     // [4096][1024]
  us* W2T   = (us*)(ws + 16 * MB);    // [1024][4096]
  us* hbuf  = (us*)(ws + 24 * MB);    // [8192][1024] bf16 (LN1 out)
  us* qkvb  = (us*)(ws + 40 * MB);    // [8192][3072] bf16
  us* ybuf  = (us*)(ws + 88 * MB);    // [8192][1024] bf16
  float* x1 = (float*)(ws + 104 * MB);// [8192][1024] f32
  us* h2    = (us*)(ws + 136 * MB);   // [8192][1024] bf16
  us* ff1   = (us*)(ws + 24 * MB);    // [8192][4096] bf16 (reuses h/qkv region)
  float* bqkv = (float*)(ws + 152 * MB); // [3072] f32

  // one fused prep dispatch: 6 transposes + bias pack + LN1 (was 8 kernels)
  prep<<<dim3(20492), 256, 0, stream>>>(Wq, Wk, Wv, Wo, W1, W2, bq, bk, bv,
                                        x, g1, be1,
                                        WqkvT, WoT, W1T, W2T, bqkv, hbuf);
  // QKV: M=8192 N=3072 K=1024 -> 32x12 = 384 blocks, BM=256 BN=256
  gemm256<<<dim3(384), 512, 0, stream>>>(hbuf, WqkvT, bqkv, qkvb, 3072, 1024, 0, 12);
  attn<<<1024, 256, 0, stream>>>(qkvb, ybuf);
  // proj: M=8192 N=1024 K=1024 -> 64x4 = 256 blocks, BM=128 BN=256, resid=x -> x1
  gemm128<<<dim3(256), 512, 0, stream>>>(ybuf, WoT, bo, x, x1, 1024, 1024, 4);
  ln_kernel<<<NTOK, 256, 0, stream>>>(x1, g2, be2, h2);
  // FF1: M=8192 N=4096 K=1024 -> 32x16 = 512 blocks, gelu
  gemm256<<<dim3(512), 512, 0, stream>>>(h2, W1T, b1, ff1, 4096, 1024, 1, 16);
  // FF2: M=8192 N=1024 K=4096 -> 64x4 = 256 blocks, resid=x1 -> out
  gemm128<<<dim3(256), 512, 0, stream>>>(ff1, W2T, b2, x1, out, 1024, 4096, 4);
}

// Round 7
// 478.463 us; speedup vs baseline: 1.3127x; 1.0172x over previous
//
#include <hip/hip_runtime.h>
#include <hip/hip_bf16.h>
#include <stdint.h>
#include <math.h>

#define SEQ 2048
#define NTOK 8192        // B*S
#define EMB 1024
#define NH 16
#define HD 64
#define FFD 4096
#define QSCALE 0.1803368801111137f   // 0.125 * log2(e), folded into Wq/bq

using us = unsigned short;
using b8 = __attribute__((ext_vector_type(8))) __bf16;
using f4 = __attribute__((ext_vector_type(4))) float;

__device__ __forceinline__ us f2b(float f) {
  union { float f; uint32_t u; } v; v.f = f;
  uint32_t u = v.u;
  return (us)((u + 0x7fffu + ((u >> 16) & 1u)) >> 16);  // RNE
}

// pack two fp32 -> bf16x2 (round-half-up; P >= 0, bias negligible)
__device__ __forceinline__ uint32_t pkbf(float a, float b) {
  union { float f; uint32_t u; } x, y; x.f = a; y.f = b;
  return ((x.u + 0x8000u) >> 16) | ((y.u + 0x8000u) & 0xFFFF0000u);
}

__device__ __forceinline__ void async16(void* lds, const void* g) {
  __builtin_amdgcn_global_load_lds(
      (__attribute__((address_space(1))) void*)(uintptr_t)g,
      (__attribute__((address_space(3))) void*)(uintptr_t)lds, 16, 0, 0);
}

#define FENCED_BARRIER() do { asm volatile("" ::: "memory"); \
  __builtin_amdgcn_s_barrier(); asm volatile("" ::: "memory"); } while (0)

// tanh-form GELU: 0.5x(1+tanh(k0(x+k1 x^3))) = x*sigmoid(2 k0 (x+k1 x^3))
// |err vs exact erf-gelu| < ~1e-3, below ff1's bf16 quantization.
__device__ __forceinline__ float gelu_f(float x) {
  const float z = -2.30211416f * x * (1.f + 0.044715f * x * x);
  return x / (1.f + __builtin_amdgcn_exp2f(z));
}

// ======= fused prep: 6 weight transposes + bias pack + LN1, ONE dispatch =======
// Block map: [0,4096) 4x 1024^2 transposes (Wq scaled by QSCALE) | [4096,8192) W1
// | [8192,12288) W2 | [12288,12300) pack_bias | [12300,20492) LN1 rows.
__global__ __launch_bounds__(256)
void prep(const float* __restrict__ Wq, const float* __restrict__ Wk,
          const float* __restrict__ Wv, const float* __restrict__ Wo,
          const float* __restrict__ W1, const float* __restrict__ W2,
          const float* __restrict__ bq, const float* __restrict__ bk,
          const float* __restrict__ bv,
          const float* __restrict__ x, const float* __restrict__ g1,
          const float* __restrict__ be1,
          us* __restrict__ WqkvT, us* __restrict__ WoT, us* __restrict__ W1T,
          us* __restrict__ W2T, float* __restrict__ bqkv, us* __restrict__ hbuf) {
  __shared__ float tile[32][33];
  __shared__ float red[8];
  const int bid = blockIdx.x;
  const int t = threadIdx.x;

  if (bid < 12288) {                       // ---- transpose+cast region ----
    int R, C, csh, t0; const float* in; us* out; float sc = 1.f;
    if (bid < 4096) {
      R = 1024; C = 1024; csh = 5; t0 = bid & 1023;
      const int m = bid >> 10;
      in  = (m == 0) ? Wq : (m == 1) ? Wk : (m == 2) ? Wv : Wo;
      out = (m == 0) ? WqkvT : (m == 1) ? (WqkvT + (1 << 20))
          : (m == 2) ? (WqkvT + (2 << 20)) : WoT;
      if (m == 0) sc = QSCALE;
    } else if (bid < 8192) {
      R = 1024; C = 4096; csh = 7; t0 = bid - 4096; in = W1; out = W1T;
    } else {
      R = 4096; C = 1024; csh = 5; t0 = bid - 8192; in = W2; out = W2T;
    }
    const int bc = (t0 & ((1 << csh) - 1)) << 5;
    const int br = (t0 >> csh) << 5;
    const int tx = t & 31, ty = t >> 5;
#pragma unroll
    for (int i = 0; i < 32; i += 8)
      tile[ty + i][tx] = in[(size_t)(br + ty + i) * C + bc + tx];
    __syncthreads();
#pragma unroll
    for (int i = 0; i < 32; i += 8)
      out[(size_t)(bc + ty + i) * R + br + tx] = f2b(tile[tx][ty + i] * sc);

  } else if (bid < 12300) {                // ---- pack_bias region ----
    const int i = (bid - 12288) * 256 + t;
    bqkv[i] = (i < 1024) ? bq[i] * QSCALE : (i < 2048 ? bk[i - 1024] : bv[i - 2048]);

  } else {                                 // ---- LN1 region ----
    const int row = bid - 12300;
    const float4 v = ((const float4*)(x + (size_t)row * EMB))[t];
    float s = v.x + v.y + v.z + v.w;
    float s2 = v.x * v.x + v.y * v.y + v.z * v.z + v.w * v.w;
#pragma unroll
    for (int o = 32; o; o >>= 1) { s += __shfl_down(s, o, 64); s2 += __shfl_down(s2, o, 64); }
    if ((t & 63) == 0) { red[(t >> 6) * 2] = s; red[(t >> 6) * 2 + 1] = s2; }
    __syncthreads();
    const float ts = red[0] + red[2] + red[4] + red[6];
    const float ts2 = red[1] + red[3] + red[5] + red[7];
    const float mu = ts * (1.f / 1024.f);
    const float rs = rsqrtf(ts2 * (1.f / 1024.f) - mu * mu + 1e-5f);
    const float4 gv = ((const float4*)g1)[t];
    const float4 bv4 = ((const float4*)be1)[t];
    ushort4 o4;
    o4.x = f2b((v.x - mu) * rs * gv.x + bv4.x);
    o4.y = f2b((v.y - mu) * rs * gv.y + bv4.y);
    o4.z = f2b((v.z - mu) * rs * gv.z + bv4.z);
    o4.w = f2b((v.w - mu) * rs * gv.w + bv4.w);
    ((ushort4*)(hbuf + (size_t)row * EMB))[t] = o4;
  }
}

// ---------------- LayerNorm: fp32 in -> bf16 out, one block per token ----------------
__global__ __launch_bounds__(256)
void ln_kernel(const float* __restrict__ x, const float* __restrict__ g,
               const float* __restrict__ be, us* __restrict__ out) {
  __shared__ float red[8];
  const int row = blockIdx.x, t = threadIdx.x;
  const float4 v = ((const float4*)(x + (size_t)row * EMB))[t];
  float s = v.x + v.y + v.z + v.w;
  float s2 = v.x * v.x + v.y * v.y + v.z * v.z + v.w * v.w;
#pragma unroll
  for (int o = 32; o; o >>= 1) { s += __shfl_down(s, o, 64); s2 += __shfl_down(s2, o, 64); }
  if ((t & 63) == 0) { red[(t >> 6) * 2] = s; red[(t >> 6) * 2 + 1] = s2; }
  __syncthreads();
  const float ts = red[0] + red[2] + red[4] + red[6];
  const float ts2 = red[1] + red[3] + red[5] + red[7];
  const float mu = ts * (1.f / 1024.f);
  const float rs = rsqrtf(ts2 * (1.f / 1024.f) - mu * mu + 1e-5f);
  const float4 gv = ((const float4*)g)[t];
  const float4 bv = ((const float4*)be)[t];
  ushort4 o4;
  o4.x = f2b((v.x - mu) * rs * gv.x + bv.x);
  o4.y = f2b((v.y - mu) * rs * gv.y + bv.y);
  o4.z = f2b((v.z - mu) * rs * gv.z + bv.z);
  o4.w = f2b((v.w - mu) * rs * gv.w + bv.w);
  ((ushort4*)(out + (size_t)row * EMB))[t] = o4;
}

// ================= GEMM 256x256, BK=64, 8 waves -- 4 barriers/K-tile =================
// Round-7 protocol: phase = {reads; BARRIER; lgkmcnt(0); MFMA; stage}. The old
// post-MFMA barrier is redundant: stage into region R only needs all waves past their
// reads of R; every wave drains reads(k) (lgkmcnt 0) BEFORE MFMA(k), which precedes
// barrier(k+1). One extra tile-boundary barrier publishes the counted-vmcnt DMA.
// Stage-slot audit (stage at END of phase, after MFMA):
//   end p1: U4(t+1) -> nxt (last read tile t-1, drained pre B_tile(t-1))     OK
//   end p2: U1(t+2) -> cur (last read p1; drained pre B2)                    OK
//   end p3: U2(t+2) -> cur (last read p1; drained pre B2 < B3)               OK
//   end p4: U3(t+2) -> cur (last read p2; drained pre B3); p4 has NO barrier OK
// vmcnt(6) at end p4 retires exactly tile t+1's 8 DMA ops (issue order: t+1 units
// precede t+2 units); B_tile then publishes t+1 to all waves before p1(t+1) reads.
// Tail: t+2>=NT skips stages; t=NT-2 drains with vmcnt(0).
__global__ __launch_bounds__(512, 2)
void gemm256(const us* __restrict__ A, const us* __restrict__ Bt,
             const float* __restrict__ bias, us* __restrict__ outB,
             int N, int K, int gelu, int gy) {
  __shared__ us As[2][256 * 64];   // 64 KB
  __shared__ us Bs[2][256 * 64];   // 64 KB

  int bid = blockIdx.x;
  const int cpx = (int)gridDim.x >> 3;         // grid % 8 == 0 always here
  bid = (bid & 7) * cpx + (bid >> 3);          // bijective XCD swizzle
  const int bx = bid / gy, by = bid - bx * gy;
  const int row0 = bx * 256, col0 = by * 256;

  const int tid = threadIdx.x, w = tid >> 6, lane = tid & 63;
  const int wm = w >> 2, wn = w & 3;
  const int quad = lane >> 4, l15 = lane & 15;
  const int xr = l15 & 7;

  const int u0 = w * 2, u1 = u0 + 1;
  const int ar0 = ((u0 & 7) << 3) + ((u0 >> 3) << 7);   // A: {0..56} + {0,128}
  const int ar1 = ((u1 & 7) << 3) + ((u1 >> 3) << 7);
  const int br0 = ((u0 & 3) << 3) + ((u0 >> 2) << 6);   // B: {0..24} + {0,64,128,192}
  const int br1 = ((u1 & 3) << 3) + ((u1 >> 2) << 6);
  const int lrow = lane >> 3;
  const int loct = ((lane & 7) ^ lrow) << 3;            // inverse-swizzled source octet
  const us* Ag0 = A + (size_t)(row0 + ar0 + lrow) * K + loct;
  const us* Ag1 = A + (size_t)(row0 + ar1 + lrow) * K + loct;
  const us* Bg0 = Bt + (size_t)(col0 + br0 + lrow) * K + loct;
  const us* Bg1 = Bt + (size_t)(col0 + br1 + lrow) * K + loct;
  const int NT = K >> 6;

  const f4 zf = {0.f, 0.f, 0.f, 0.f};
  f4 acc[8][4];
#pragma unroll
  for (int i = 0; i < 8; i++)
#pragma unroll
    for (int j = 0; j < 4; j++) acc[i][j] = zf;

  auto stgA = [&](int buf, int t, int mh) {
    const size_t go = (size_t)(mh << 6) * K + ((size_t)t << 6);
    async16(&As[buf][(ar0 + (mh << 6)) << 6], Ag0 + go);
    async16(&As[buf][(ar1 + (mh << 6)) << 6], Ag1 + go);
  };
  auto stgB = [&](int buf, int t, int nh) {
    const size_t go = (size_t)(nh << 5) * K + ((size_t)t << 6);
    async16(&Bs[buf][(br0 + (nh << 5)) << 6], Bg0 + go);
    async16(&Bs[buf][(br1 + (nh << 5)) << 6], Bg1 + go);
  };

  // prologue: t0 fully (8 ops) + t1 U1,U2,U3 (6 ops); drain t0, keep 6 in flight
  stgA(0, 0, 0); stgB(0, 0, 0); stgB(0, 0, 1); stgA(0, 0, 1);
  stgA(1, 1, 0); stgB(1, 1, 0); stgB(1, 1, 1);
  asm volatile("s_waitcnt vmcnt(6)" ::: "memory");
  FENCED_BARRIER();

  for (int t = 0; t < NT; t++) {
    const int cur = t & 1, nxt = cur ^ 1;
    const us* __restrict__ as = As[cur];
    const us* __restrict__ bs = Bs[cur];
    b8 af[2][4], bf0[2][2], bf1[2][2];

    // ---- phase 1: reads af(mh0)+bf0 (12), B1, MFMA q00, stage U4(t+1)
#pragma unroll
    for (int s = 0; s < 2; s++) {
      const int po = (((s << 2) + quad) ^ xr) << 3;
#pragma unroll
      for (int mi = 0; mi < 4; mi++)
        af[s][mi] = *(const b8*)&as[(wm * 128 + mi * 16 + l15) * 64 + po];
#pragma unroll
      for (int nf = 0; nf < 2; nf++)
        bf0[s][nf] = *(const b8*)&bs[(wn * 64 + nf * 16 + l15) * 64 + po];
    }
    FENCED_BARRIER();
    asm volatile("s_waitcnt lgkmcnt(0)" ::: "memory");
    __builtin_amdgcn_s_setprio(1);
#pragma unroll
    for (int s = 0; s < 2; s++)
#pragma unroll
      for (int mi = 0; mi < 4; mi++)
#pragma unroll
        for (int nf = 0; nf < 2; nf++)
          acc[mi][nf] = __builtin_amdgcn_mfma_f32_16x16x32_bf16(af[s][mi], bf0[s][nf], acc[mi][nf], 0, 0, 0);
    __builtin_amdgcn_s_setprio(0);
    if (t + 1 < NT) stgA(nxt, t + 1, 1);

    // ---- phase 2: reads bf1 (4), B2, MFMA q01, stage U1(t+2)
#pragma unroll
    for (int s = 0; s < 2; s++) {
      const int po = (((s << 2) + quad) ^ xr) << 3;
#pragma unroll
      for (int nf = 0; nf < 2; nf++)
        bf1[s][nf] = *(const b8*)&bs[(wn * 64 + 32 + nf * 16 + l15) * 64 + po];
    }
    FENCED_BARRIER();
    asm volatile("s_waitcnt lgkmcnt(0)" ::: "memory");
    __builtin_amdgcn_s_setprio(1);
#pragma unroll
    for (int s = 0; s < 2; s++)
#pragma unroll
      for (int mi = 0; mi < 4; mi++)
#pragma unroll
        for (int nf = 0; nf < 2; nf++)
          acc[mi][2 + nf] = __builtin_amdgcn_mfma_f32_16x16x32_bf16(af[s][mi], bf1[s][nf], acc[mi][2 + nf], 0, 0, 0);
    __builtin_amdgcn_s_setprio(0);
    if (t + 2 < NT) stgA(cur, t + 2, 0);

    // ---- phase 3: reads af(mh1) (8), B3, MFMA q10, stage U2(t+2)
#pragma unroll
    for (int s = 0; s < 2; s++) {
      const int po = (((s << 2) + quad) ^ xr) << 3;
#pragma unroll
      for (int mi = 0; mi < 4; mi++)
        af[s][mi] = *(const b8*)&as[(wm * 128 + 64 + mi * 16 + l15) * 64 + po];
    }
    FENCED_BARRIER();
    asm volatile("s_waitcnt lgkmcnt(0)" ::: "memory");
    __builtin_amdgcn_s_setprio(1);
#pragma unroll
    for (int s = 0; s < 2; s++)
#pragma unroll
      for (int mi = 0; mi < 4; mi++)
#pragma unroll
        for (int nf = 0; nf < 2; nf++)
          acc[4 + mi][nf] = __builtin_amdgcn_mfma_f32_16x16x32_bf16(af[s][mi], bf0[s][nf], acc[4 + mi][nf], 0, 0, 0);
    __builtin_amdgcn_s_setprio(0);
    if (t + 2 < NT) stgB(cur, t + 2, 0);

    // ---- phase 4 (no barrier): MFMA q11, stage U3(t+2), counted vmcnt, tile barrier
    __builtin_amdgcn_s_setprio(1);
#pragma unroll
    for (int s = 0; s < 2; s++)
#pragma unroll
      for (int mi = 0; mi < 4; mi++)
#pragma unroll
        for (int nf = 0; nf < 2; nf++)
          acc[4 + mi][2 + nf] = __builtin_amdgcn_mfma_f32_16x16x32_bf16(af[s][mi], bf1[s][nf], acc[4 + mi][2 + nf], 0, 0, 0);
    __builtin_amdgcn_s_setprio(0);
    if (t + 2 < NT) {
      stgB(cur, t + 2, 1);
      asm volatile("s_waitcnt vmcnt(6)" ::: "memory");   // retires all of tile t+1
    } else {
      asm volatile("s_waitcnt vmcnt(0)" ::: "memory");
    }
    FENCED_BARRIER();   // B_tile: publish t+1 DMA before its reads
  }

#pragma unroll
  for (int mi8 = 0; mi8 < 8; mi8++)
#pragma unroll
    for (int nf = 0; nf < 4; nf++) {
      const int gcol = col0 + wn * 64 + nf * 16 + l15;
      const float bc = bias[gcol];
#pragma unroll
      for (int r = 0; r < 4; r++) {
        const int grow = row0 + wm * 128 + mi8 * 16 + quad * 4 + r;
        float v = acc[mi8][nf][r] + bc;
        if (gelu) v = gelu_f(v);
        outB[(size_t)grow * N + gcol] = f2b(v);
      }
    }
}

// ================= GEMM 128x256 (f32 out + resid) -- 3 barriers/K-tile ==================
// Same single-barrier-per-phase protocol. Slots: end p1: UB1(t+1)->nxt (safe);
// end p2: UA(t+2),UB0(t+2)->cur (last read p1, drained pre B2); vmcnt(4) retires
// exactly tile t+1's 6 ops (order: UB1(t+1)@p1 precedes t+2 units); B_tile publishes.
__global__ __launch_bounds__(512, 2)
void gemm128(const us* __restrict__ A, const us* __restrict__ Bt,
             const float* __restrict__ bias, const float* __restrict__ resid,
             float* __restrict__ outF, int N, int K, int gy) {
  __shared__ us As[2][128 * 64];   // 32 KB
  __shared__ us Bs[2][256 * 64];   // 64 KB

  int bid = blockIdx.x;
  const int cpx = (int)gridDim.x >> 3;
  bid = (bid & 7) * cpx + (bid >> 3);
  const int bx = bid / gy, by = bid - bx * gy;
  const int row0 = bx * 128, col0 = by * 256;

  const int tid = threadIdx.x, w = tid >> 6, lane = tid & 63;
  const int wm = w >> 2, wn = w & 3;
  const int quad = lane >> 4, l15 = lane & 15;
  const int xr = l15 & 7;

  const int u0 = w * 2, u1 = u0 + 1;
  const int aR0 = u0 << 3, aR1 = u1 << 3;               // A rows 0..127
  const int bR0 = ((u0 & 3) << 3) + ((u0 >> 2) << 6);
  const int bR1 = ((u1 & 3) << 3) + ((u1 >> 2) << 6);
  const int lrow = lane >> 3;
  const int loct = ((lane & 7) ^ lrow) << 3;
  const us* Ag0 = A + (size_t)(row0 + aR0 + lrow) * K + loct;
  const us* Ag1 = A + (size_t)(row0 + aR1 + lrow) * K + loct;
  const us* Bg0 = Bt + (size_t)(col0 + bR0 + lrow) * K + loct;
  const us* Bg1 = Bt + (size_t)(col0 + bR1 + lrow) * K + loct;
  const int NT = K >> 6;

  const f4 zf = {0.f, 0.f, 0.f, 0.f};
  f4 acc[4][4];
#pragma unroll
  for (int i = 0; i < 4; i++)
#pragma unroll
    for (int j = 0; j < 4; j++) acc[i][j] = zf;

  auto stgA = [&](int buf, int t) {
    const size_t go = (size_t)t << 6;
    async16(&As[buf][aR0 << 6], Ag0 + go);
    async16(&As[buf][aR1 << 6], Ag1 + go);
  };
  auto stgB = [&](int buf, int t, int nh) {
    const size_t go = (size_t)(nh << 5) * K + ((size_t)t << 6);
    async16(&Bs[buf][(bR0 + (nh << 5)) << 6], Bg0 + go);
    async16(&Bs[buf][(bR1 + (nh << 5)) << 6], Bg1 + go);
  };

  // prologue: t0 (6 ops) + t1 UA,UB0 (4 ops); vmcnt(4) retires t0's 6
  stgA(0, 0); stgB(0, 0, 0); stgB(0, 0, 1);
  stgA(1, 1); stgB(1, 1, 0);
  asm volatile("s_waitcnt vmcnt(4)" ::: "memory");
  FENCED_BARRIER();

  for (int t = 0; t < NT; t++) {
    const int cur = t & 1, nxt = cur ^ 1;
    const us* __restrict__ as = As[cur];
    const us* __restrict__ bs = Bs[cur];
    b8 af[2][4], bf0[2][2], bf1[2][2];

    // ---- phase 1: reads af+bf0 (12), B1, MFMA, stage UB1(t+1)
#pragma unroll
    for (int s = 0; s < 2; s++) {
      const int po = (((s << 2) + quad) ^ xr) << 3;
#pragma unroll
      for (int mi = 0; mi < 4; mi++)
        af[s][mi] = *(const b8*)&as[(wm * 64 + mi * 16 + l15) * 64 + po];
#pragma unroll
      for (int nf = 0; nf < 2; nf++)
        bf0[s][nf] = *(const b8*)&bs[(wn * 64 + nf * 16 + l15) * 64 + po];
    }
    FENCED_BARRIER();
    asm volatile("s_waitcnt lgkmcnt(0)" ::: "memory");
    __builtin_amdgcn_s_setprio(1);
#pragma unroll
    for (int s = 0; s < 2; s++)
#pragma unroll
      for (int mi = 0; mi < 4; mi++)
#pragma unroll
        for (int nf = 0; nf < 2; nf++)
          acc[mi][nf] = __builtin_amdgcn_mfma_f32_16x16x32_bf16(af[s][mi], bf0[s][nf], acc[mi][nf], 0, 0, 0);
    __builtin_amdgcn_s_setprio(0);
    if (t + 1 < NT) stgB(nxt, t + 1, 1);

    // ---- phase 2: reads bf1 (4), B2, MFMA, stage UA+UB0(t+2), vmcnt(4), B_tile
#pragma unroll
    for (int s = 0; s < 2; s++) {
      const int po = (((s << 2) + quad) ^ xr) << 3;
#pragma unroll
      for (int nf = 0; nf < 2; nf++)
        bf1[s][nf] = *(const b8*)&bs[(wn * 64 + 32 + nf * 16 + l15) * 64 + po];
    }
    FENCED_BARRIER();
    asm volatile("s_waitcnt lgkmcnt(0)" ::: "memory");
    __builtin_amdgcn_s_setprio(1);
#pragma unroll
    for (int s = 0; s < 2; s++)
#pragma unroll
      for (int mi = 0; mi < 4; mi++)
#pragma unroll
        for (int nf = 0; nf < 2; nf++)
          acc[mi][2 + nf] = __builtin_amdgcn_mfma_f32_16x16x32_bf16(af[s][mi], bf1[s][nf], acc[mi][2 + nf], 0, 0, 0);
    __builtin_amdgcn_s_setprio(0);
    if (t + 2 < NT) {
      stgA(cur, t + 2); stgB(cur, t + 2, 0);
      asm volatile("s_waitcnt vmcnt(4)" ::: "memory");   // retires all of tile t+1
    } else {
      asm volatile("s_waitcnt vmcnt(0)" ::: "memory");
    }
    FENCED_BARRIER();   // B_tile
  }

#pragma unroll
  for (int mi = 0; mi < 4; mi++)
#pragma unroll
    for (int nf = 0; nf < 4; nf++) {
      const int gcol = col0 + wn * 64 + nf * 16 + l15;
      const float bc = bias[gcol];
#pragma unroll
      for (int r = 0; r < 4; r++) {
        const int grow = row0 + wm * 64 + mi * 16 + quad * 4 + r;
        outF[(size_t)grow * N + gcol] = acc[mi][nf][r] + bc + resid[(size_t)grow * N + gcol];
      }
    }
}

// ---------------- causal flash attention (unchanged from round 6) ----------------
__global__ __launch_bounds__(256, 3)
void attn(const us* __restrict__ qkv, us* __restrict__ y) {
  static const signed char QTM[16] = {15,14,13,12, 10,11,8,9, 5,4,7,6, 0,1,2,3};
  const int bx = blockIdx.x;
  const int bh = bx & 63;
  const int qt = QTM[(bx >> 6) & 15];
  const int bb = bh >> 4, h = bh & 15;
  const int tid = threadIdx.x;
  const int wave = tid >> 6, lane = tid & 63;
  const int quad = lane >> 4, l15 = lane & 15;

  __shared__ us Ks[128 * 64];      // 16 KB; phys us off = row*64 + ((col8 ^ (row&7))<<3)
  __shared__ us Vt[2][64 * 132];   // 33 KB; V^T[d][key], us off = d*132 + key

  const size_t base = (size_t)bb * SEQ * 3072;
  const int q0 = qt * 128;

  b8 bqf[2][2];
#pragma unroll
  for (int qg = 0; qg < 2; qg++) {
    const us* qp = qkv + base + (size_t)(q0 + wave * 32 + qg * 16 + l15) * 3072 + h * 64 + quad * 8;
    bqf[qg][0] = *(const b8*)qp;
    bqf[qg][1] = *(const b8*)(qp + 32);
  }

  const f4 zf = {0.f, 0.f, 0.f, 0.f};
  f4 o[2][4];
  float mrow[2], lrow[2];
#pragma unroll
  for (int qg = 0; qg < 2; qg++) {
    mrow[qg] = -3.0e38f; lrow[qg] = 0.f;
#pragma unroll
    for (int dg = 0; dg < 4; dg++) o[qg][dg] = zf;
  }

  const int klr = lane >> 3, klc = lane & 7;
  const us* kgbase = qkv + base + (size_t)(wave * 32 + klr) * 3072 + 1024 + h * 64 + ((klc ^ klr) << 3);
  const us* vgbase = qkv + base + (size_t)(2 * lane) * 3072 + 2048 + h * 64 + wave * 8;

  {
    union { float4 f; us u[8]; } v0, v1, v2, v3;
    v0.f = *(const float4*)(vgbase);
    v1.f = *(const float4*)(vgbase + 3072);
    v2.f = *(const float4*)(vgbase + 32);
    v3.f = *(const float4*)(vgbase + 3072 + 32);
#pragma unroll
    for (int j = 0; j < 8; j++) {
      *(uint32_t*)&Vt[0][(wave * 8 + j) * 132 + 2 * lane] =
          (uint32_t)v0.u[j] | ((uint32_t)v1.u[j] << 16);
      *(uint32_t*)&Vt[0][(32 + wave * 8 + j) * 132 + 2 * lane] =
          (uint32_t)v2.u[j] | ((uint32_t)v3.u[j] << 16);
    }
  }

  for (int kt = 0; kt <= qt; kt++) {
    const int cur = kt & 1, nxt = cur ^ 1;
    const size_t koff = (size_t)kt * 128 * 3072;
#pragma unroll
    for (int op = 0; op < 4; op++)
      async16(&Ks[(wave * 32 + op * 8) * 64], kgbase + koff + (size_t)op * 8 * 3072);
    float4 vb0, vb1, vb2, vb3;
    if (kt < qt) {
      const us* vg = vgbase + koff + (size_t)128 * 3072;
      vb0 = *(const float4*)(vg);
      vb1 = *(const float4*)(vg + 3072);
      vb2 = *(const float4*)(vg + 32);
      vb3 = *(const float4*)(vg + 3072 + 32);
      asm volatile("s_waitcnt vmcnt(4)" ::: "memory");
    } else {
      asm volatile("s_waitcnt vmcnt(0)" ::: "memory");
    }
    asm volatile("s_waitcnt lgkmcnt(0)" ::: "memory");
    FENCED_BARRIER();

    f4 sacc[2][8];
    __builtin_amdgcn_s_setprio(1);
#pragma unroll
    for (int c = 0; c < 8; c++) {
      const int krow = (c * 16 + l15) * 64;
      const int sw = l15 & 7;
      const b8 ak0 = *(const b8*)&Ks[krow + ((quad ^ sw) << 3)];
      const b8 ak1 = *(const b8*)&Ks[krow + (((quad ^ 4) ^ sw) << 3)];
#pragma unroll
      for (int qg = 0; qg < 2; qg++) {
        f4 s = __builtin_amdgcn_mfma_f32_16x16x32_bf16(ak0, bqf[qg][0], zf, 0, 0, 0);
        sacc[qg][c] = __builtin_amdgcn_mfma_f32_16x16x32_bf16(ak1, bqf[qg][1], s, 0, 0, 0);
      }
    }
    __builtin_amdgcn_s_setprio(0);

    uint32_t pf[2][16];
#pragma unroll
    for (int qg = 0; qg < 2; qg++) {
      const int q_in = wave * 32 + qg * 16 + l15;
      if (kt == qt) {
#pragma unroll
        for (int c = 0; c < 8; c++)
#pragma unroll
          for (int r = 0; r < 4; r++)
            if ((c * 16 + quad * 4 + r) > q_in) sacc[qg][c][r] = -3.0e38f;
      }
      float mx = sacc[qg][0][0];
#pragma unroll
      for (int c = 0; c < 8; c++)
#pragma unroll
        for (int r = 0; r < 4; r++) mx = fmaxf(mx, sacc[qg][c][r]);
      mx = fmaxf(mx, __shfl_xor(mx, 16, 64));
      mx = fmaxf(mx, __shfl_xor(mx, 32, 64));
      if (!__all(mx - mrow[qg] <= 8.f)) {
        const float mnew = fmaxf(mrow[qg], mx);
        const float al = __builtin_amdgcn_exp2f(mrow[qg] - mnew);
        mrow[qg] = mnew;
        lrow[qg] *= al;
#pragma unroll
        for (int r = 0; r < 4; r++) {
          const float ar = __shfl(al, quad * 4 + r, 64);
#pragma unroll
          for (int dg = 0; dg < 4; dg++) o[qg][dg][r] *= ar;
        }
      }
      const float mb = mrow[qg];
      float rs = 0.f;
#pragma unroll
      for (int c = 0; c < 8; c++) {
        const float p0 = __builtin_amdgcn_exp2f(sacc[qg][c][0] - mb);
        const float p1 = __builtin_amdgcn_exp2f(sacc[qg][c][1] - mb);
        const float p2 = __builtin_amdgcn_exp2f(sacc[qg][c][2] - mb);
        const float p3 = __builtin_amdgcn_exp2f(sacc[qg][c][3] - mb);
        rs += (p0 + p1) + (p2 + p3);
        pf[qg][c * 2] = pkbf(p0, p1);
        pf[qg][c * 2 + 1] = pkbf(p2, p3);
      }
      rs += __shfl_xor(rs, 16, 64);
      rs += __shfl_xor(rs, 32, 64);
      lrow[qg] += rs;
    }

    if (kt < qt) {
      asm volatile("s_waitcnt vmcnt(0)" ::: "memory");
      union { float4 f; us u[8]; } v0, v1, v2, v3;
      v0.f = vb0; v1.f = vb1; v2.f = vb2; v3.f = vb3;
#pragma unroll
      for (int j = 0; j < 8; j++) {
        *(uint32_t*)&Vt[nxt][(wave * 8 + j) * 132 + 2 * lane] =
            (uint32_t)v0.u[j] | ((uint32_t)v1.u[j] << 16);
        *(uint32_t*)&Vt[nxt][(32 + wave * 8 + j) * 132 + 2 * lane] =
            (uint32_t)v2.u[j] | ((uint32_t)v3.u[j] << 16);
      }
    }

    __builtin_amdgcn_s_setprio(1);
#pragma unroll
    for (int c = 0; c < 8; c++) {
      union { uint32_t w[4]; b8 v; } af0, af1;
      af0.w[0] = pf[0][c * 2]; af0.w[1] = pf[0][c * 2 + 1]; af0.w[2] = 0u; af0.w[3] = 0u;
      af1.w[0] = pf[1][c * 2]; af1.w[1] = pf[1][c * 2 + 1]; af1.w[2] = 0u; af1.w[3] = 0u;
#pragma unroll
      for (int dg = 0; dg < 4; dg++) {
        const uint2 vd = *(const uint2*)&Vt[cur][(dg * 16 + l15) * 132 + c * 16 + quad * 4];
        union { uint32_t w[4]; b8 v; } vb;
        vb.w[0] = vd.x; vb.w[1] = vd.y; vb.w[2] = 0u; vb.w[3] = 0u;
        o[0][dg] = __builtin_amdgcn_mfma_f32_16x16x32_bf16(af0.v, vb.v, o[0][dg], 0, 0, 0);
        o[1][dg] = __builtin_amdgcn_mfma_f32_16x16x32_bf16(af1.v, vb.v, o[1][dg], 0, 0, 0);
      }
    }
    __builtin_amdgcn_s_setprio(0);
    asm volatile("s_waitcnt lgkmcnt(0)" ::: "memory");
    FENCED_BARRIER();
  }

#pragma unroll
  for (int qg = 0; qg < 2; qg++) {
    float lr[4];
#pragma unroll
    for (int r = 0; r < 4; r++) lr[r] = __shfl(lrow[qg], quad * 4 + r, 64);
#pragma unroll
    for (int dg = 0; dg < 4; dg++)
#pragma unroll
      for (int r = 0; r < 4; r++) {
        const int gq = q0 + wave * 32 + qg * 16 + quad * 4 + r;
        y[(size_t)(bb * SEQ + gq) * EMB + h * 64 + dg * 16 + l15] = f2b(o[qg][dg][r] / lr[r]);
      }
  }
}

extern "C" void kernel_launch(void* const* d_in, const int* in_sizes, int n_in,
                              void* d_out, int out_size, void* d_ws, size_t ws_size,
                              hipStream_t stream) {
  const float* x = (const float*)d_in[0];
  const float* Wq = (const float*)d_in[1];
  const float* bq = (const float*)d_in[2];
  const float* Wk = (const float*)d_in[3];
  const float* bk = (const float*)d_in[4];
  const float* Wv = (const float*)d_in[5];
  const float* bv = (const float*)d_in[6];
  const float* Wo = (const float*)d_in[7];
  const float* bo = (const float*)d_in[8];
  const float* g1 = (const float*)d_in[9];
  const float* be1 = (const float*)d_in[10];
  const float* g2 = (const float*)d_in[11];
  const float* be2 = (const float*)d_in[12];
  const float* W1 = (const float*)d_in[13];
  const float* b1 = (const float*)d_in[14];
  const float* W2 = (const float*)d_in[15];
  const float* b2 = (const float*)d_in[16];
  float* out = (float*)d_out;

  char* ws = (char*)d_ws;
  const size_t MB = 1024ull * 1024ull;
  us* WqkvT = (us*)(ws + 0);          // [3072][1024] bf16
  us* WoT   = (us*)(ws + 6 * MB);     // [1024][1024]
  us* W1T   = (us*)(ws + 8 * MB);     // [4096][1024]
  us* W2T   = (us*)(ws + 16 * MB);    // [1024][4096]
  us* hbuf  = (us*)(ws + 24 * MB);    // [8192][1024] bf16 (LN1 out)
  us* qkvb  = (us*)(ws + 40 * MB);    // [8192][3072] bf16
  us* ybuf  = (us*)(ws + 88 * MB);    // [8192][1024] bf16
  float* x1 = (float*)(ws + 104 * MB);// [8192][1024] f32
  us* h2    = (us*)(ws + 136 * MB);   // [8192][1024] bf16
  us* ff1   = (us*)(ws + 24 * MB);    // [8192][4096] bf16 (reuses h/qkv region)
  float* bqkv = (float*)(ws + 152 * MB); // [3072] f32

  // one fused prep dispatch: 6 transposes + bias pack + LN1
  prep<<<dim3(20492), 256, 0, stream>>>(Wq, Wk, Wv, Wo, W1, W2, bq, bk, bv,
                                        x, g1, be1,
                                        WqkvT, WoT, W1T, W2T, bqkv, hbuf);
  // QKV: M=8192 N=3072 K=1024 -> 32x12 = 384 blocks, BM=256 BN=256
  gemm256<<<dim3(384), 512, 0, stream>>>(hbuf, WqkvT, bqkv, qkvb, 3072, 1024, 0, 12);
  attn<<<1024, 256, 0, stream>>>(qkvb, ybuf);
  // proj: M=8192 N=1024 K=1024 -> 64x4 = 256 blocks, BM=128 BN=256, resid=x -> x1
  gemm128<<<dim3(256), 512, 0, stream>>>(ybuf, WoT, bo, x, x1, 1024, 1024, 4);
  ln_kernel<<<NTOK, 256, 0, stream>>>(x1, g2, be2, h2);
  // FF1: M=8192 N=4096 K=1024 -> 32x16 = 512 blocks, gelu
  gemm256<<<dim3(512), 512, 0, stream>>>(h2, W1T, b1, ff1, 4096, 1024, 1, 16);
  // FF2: M=8192 N=1024 K=4096 -> 64x4 = 256 blocks, resid=x1 -> out
  gemm128<<<dim3(256), 512, 0, stream>>>(ff1, W2T, b2, x1, out, 1024, 4096, 4);
}